// Round 4
// baseline (415.860 us; speedup 1.0000x reference)
//
#include <hip/hip_runtime.h>
#include <hip/hip_bf16.h>
#include <math.h>

// N=768, H=4, D=3, HDIM=64, HID=64. e_in[i,j] = [sqn(4) | hc[j](80) | hc[i](80)]
// z0 = [W0a | I] @ [sqn | Bj[j]] + Bi[i]   (Bi includes b0 + hc[i] half; I = identity
// transports Bj into MFMA C-layout). Weights live in global (L1/L2-hot), activations
// round-trip a per-wave LDS buffer [p][k] stride 72. m_i accumulated in registers.
//
// ws layout (float offsets):
#define WS_BI    0         // Bi [768][64] f32
#define WS_BIAS  49152     // [224] f32: eb1(0) xb0(64) infb(128) 0(129..143) xb1(144) xb2(208) 0
#define WS_L0A   49376     // bf16 [64 rows][96]: k0..3=W0a, 4..31=0, 32..95=I
#define WS_WG    52448     // bf16 [224 rows][64]: W1^T@0, X0^T@64, infw@128, 0, X1^T@144, X2^T@208, 0
#define WS_BJB   59616     // bf16 Bj [768][64]

typedef unsigned short ushort_t;
typedef __attribute__((ext_vector_type(8))) __bf16 bf16x8;
typedef __attribute__((ext_vector_type(4))) float f32x4;

union B8U { uint4 u; bf16x8 v; };

__device__ __forceinline__ float silu_f(float v) { return v / (1.0f + __expf(-v)); }

__device__ __forceinline__ ushort_t bf16r(float f) {
    unsigned u = __float_as_uint(f);
    u += 0x7FFFu + ((u >> 16) & 1u);
    return (ushort_t)(u >> 16);
}
__device__ __forceinline__ unsigned pk2(float a, float b) {
    __hip_bfloat162 t = __float22bfloat162_rn(make_float2(a, b));
    return *reinterpret_cast<unsigned*>(&t);
}

// ---------------- prep ----------------
__global__ __launch_bounds__(64) void prep_kernel(
    const float* __restrict__ x, const float* __restrict__ h,
    const float* __restrict__ ew0, const float* __restrict__ eb0,
    const float* __restrict__ ew1, const float* __restrict__ eb1,
    const float* __restrict__ infw, const float* __restrict__ infb,
    const float* __restrict__ xw0, const float* __restrict__ xb0,
    const float* __restrict__ xw1, const float* __restrict__ xb1,
    const float* __restrict__ xw2, const float* __restrict__ xb2,
    float* __restrict__ ws)
{
    const int blk = blockIdx.x, t = threadIdx.x;
    if (blk < 768) {
        __shared__ float hcs[80];
        const int m = blk;
        hcs[t] = h[m * 64 + t];
        if (t < 16) {
            int i2 = t >> 2, j2 = t & 3;
            float d0 = x[m*12 + j2*3 + 0] - x[m*12 + i2*3 + 0];
            float d1 = x[m*12 + j2*3 + 1] - x[m*12 + i2*3 + 1];
            float d2 = x[m*12 + j2*3 + 2] - x[m*12 + i2*3 + 2];
            hcs[64 + t] = d0*d0 + d1*d1 + d2*d2;
        }
        __syncthreads();
        float bj = 0.0f, bi = eb0[t];
        #pragma unroll 4
        for (int k = 0; k < 80; ++k) {
            float hv = hcs[k];
            bj += hv * ew0[(4 + k) * 64 + t];
            bi += hv * ew0[(84 + k) * 64 + t];
        }
        ws[WS_BI + m * 64 + t] = bi;
        ((ushort_t*)(ws + WS_BJB))[m * 64 + t] = bf16r(bj);
    } else if (blk == 768) {
        #pragma unroll
        for (int u = 0; u < 4; ++u) {
            int idx = u * 64 + t;
            if (idx < 224) {
                float v;
                if (idx < 64)        v = eb1[idx];
                else if (idx < 128)  v = xb0[idx - 64];
                else if (idx == 128) v = infb[0];
                else if (idx < 144)  v = 0.0f;
                else if (idx < 208)  v = xb1[idx - 144];
                else if (idx < 212)  v = xb2[idx - 208];
                else                 v = 0.0f;
                ws[WS_BIAS + idx] = v;
            }
        }
    } else if (blk < 781) {
        ushort_t* l0a = (ushort_t*)(ws + WS_L0A);
        #pragma unroll 1
        for (int u = 0; u < 8; ++u) {
            int e = (blk - 769) * 512 + u * 64 + t;    // < 6144
            int r = e / 96, c = e - r * 96;
            float v;
            if (c < 4)       v = ew0[c * 64 + r];
            else if (c < 32) v = 0.0f;
            else             v = (c - 32 == r) ? 1.0f : 0.0f;
            l0a[e] = bf16r(v);
        }
    } else {
        ushort_t* wg = (ushort_t*)(ws + WS_WG);
        #pragma unroll 1
        for (int u = 0; u < 8; ++u) {
            int e = (blk - 781) * 512 + u * 64 + t;    // < 14336
            int r = e >> 6, k = e & 63;
            float v;
            if (r < 64)        v = ew1[k * 64 + r];
            else if (r < 128)  v = xw0[k * 64 + (r - 64)];
            else if (r == 128) v = infw[k];
            else if (r < 144)  v = 0.0f;
            else if (r < 208)  v = xw1[k * 64 + (r - 144)];
            else if (r < 212)  v = xw2[k * 4 + (r - 208)];
            else               v = 0.0f;
            wg[e] = bf16r(v);
        }
    }
}

// B-frags from per-wave LDS activations [p][k], stride 72
__device__ __forceinline__ void load_bfrags(const ushort_t* yb, int ml, int q, bf16x8 B[4][2]) {
    #pragma unroll
    for (int pt = 0; pt < 4; ++pt)
        #pragma unroll
        for (int kt = 0; kt < 2; ++kt)
            B[pt][kt] = *(const bf16x8*)(yb + (pt*16 + ml) * 72 + kt*32 + q*8);
}

// A-frags from GLOBAL weight image (rows x 64, row-major)
template<int NMT>
__device__ __forceinline__ void gemmG(const ushort_t* __restrict__ wg, int ml, int q,
                                      const bf16x8 B[4][2], f32x4* acc) {
    #pragma unroll
    for (int mt = 0; mt < NMT; ++mt) {
        #pragma unroll
        for (int kt = 0; kt < 2; ++kt) {
            bf16x8 af = *(const bf16x8*)(wg + (mt*16 + ml) * 64 + kt*32 + q*8);
            #pragma unroll
            for (int pt = 0; pt < 4; ++pt)
                acc[mt*4 + pt] = __builtin_amdgcn_mfma_f32_16x16x32_bf16(af, B[pt][kt], acc[mt*4 + pt], 0, 0, 0);
        }
    }
}

// epilogue: y[p][n'] = bf16(silu(acc + bias)); optionally capture packed words
template<bool CAP>
__device__ __forceinline__ void ep_silu4(ushort_t* yb, int ml, int q,
                                         const f32x4* acc, const float4* bias, uint2* cap) {
    #pragma unroll
    for (int mt = 0; mt < 4; ++mt) {
        float4 bv = bias[mt];
        #pragma unroll
        for (int pt = 0; pt < 4; ++pt) {
            f32x4 a = acc[mt*4 + pt];
            uint2 w = make_uint2(pk2(silu_f(a[0] + bv.x), silu_f(a[1] + bv.y)),
                                 pk2(silu_f(a[2] + bv.z), silu_f(a[3] + bv.w)));
            if (CAP) cap[mt*4 + pt] = w;
            *(uint2*)(yb + (pt*16 + ml) * 72 + mt*16 + q*4) = w;
        }
    }
}

// ---------------- main fused kernel: one block per row i ----------------
__global__ __launch_bounds__(256, 3) void egcl_kernel(
    const float* __restrict__ x, const float* __restrict__ h,
    const float* __restrict__ hw0, const float* __restrict__ hb0,
    const float* __restrict__ hw1, const float* __restrict__ hb1,
    const float* __restrict__ hw2, const float* __restrict__ hb2,
    const float* __restrict__ ws, float* __restrict__ out)
{
    __shared__ ushort_t ybuf[4][4608];    // per-wave acts [64 p][72]
    __shared__ ushort_t sqbuf[4][256];    // per-wave sqn bf16 [64 p][4]
    __shared__ float sbuf[4][64];
    __shared__ float pbuf[4][256];
    __shared__ float redm[4][64];
    __shared__ float reds[4][12];
    __shared__ float inbuf[128];
    __shared__ float zbuf[64];

    const int i = blockIdx.x, tid = threadIdx.x;
    const int wv = tid >> 6, lane = tid & 63;
    const int ml = lane & 15, q = lane >> 4;

    const ushort_t* l0a = (const ushort_t*)(ws + WS_L0A);
    const ushort_t* wg  = (const ushort_t*)(ws + WS_WG);
    const ushort_t* bjb = (const ushort_t*)(ws + WS_BJB);

    if (wv == 1) inbuf[64 + lane] = h[i * 64 + lane];

    // per-lane bias/Bi fragments (n' = mt*16 + q*4 + reg)
    const float* bias = ws + WS_BIAS;
    float4 b_l1[4], b_x0[4], b_x1[4], b_x2, bi4[4];
    #pragma unroll
    for (int mt = 0; mt < 4; ++mt) {
        b_l1[mt] = *(const float4*)(bias + 0   + mt*16 + q*4);
        b_x0[mt] = *(const float4*)(bias + 64  + mt*16 + q*4);
        b_x1[mt] = *(const float4*)(bias + 144 + mt*16 + q*4);
        bi4[mt]  = *(const float4*)(ws + WS_BI + i*64 + mt*16 + q*4);
    }
    b_x2 = *(const float4*)(bias + 208 + q*4);
    const float binf = bias[128];

    float xi[12];
    #pragma unroll
    for (int t = 0; t < 12; ++t) xi[t] = x[i * 12 + t];

    ushort_t* yb = ybuf[wv];
    ushort_t* sq = sqbuf[wv];

    float macc[16];
    #pragma unroll
    for (int t = 0; t < 16; ++t) macc[t] = 0.0f;
    float sacc[12];
    #pragma unroll
    for (int t = 0; t < 12; ++t) sacc[t] = 0.0f;

    #pragma unroll 1
    for (int it = 0; it < 3; ++it) {
        const int jbase = it * 256 + wv * 64;
        const int jg = jbase + lane;

        float dx[12];
        {
            const float4* xp = (const float4*)(x + jg * 12);
            float4 a = xp[0], b = xp[1], c = xp[2];
            dx[0]=a.x-xi[0]; dx[1]=a.y-xi[1]; dx[2]=a.z-xi[2];  dx[3]=a.w-xi[3];
            dx[4]=b.x-xi[4]; dx[5]=b.y-xi[5]; dx[6]=b.z-xi[6];  dx[7]=b.w-xi[7];
            dx[8]=c.x-xi[8]; dx[9]=c.y-xi[9]; dx[10]=c.z-xi[10];dx[11]=c.w-xi[11];
        }
        float sqn[4];
        #pragma unroll
        for (int hh = 0; hh < 4; ++hh)
            sqn[hh] = dx[hh*3]*dx[hh*3] + dx[hh*3+1]*dx[hh*3+1] + dx[hh*3+2]*dx[hh*3+2];

        // stage sqn (bf16 x4) for L0 B-frags
        *(uint2*)(sq + lane * 4) = make_uint2(pk2(sqn[0], sqn[1]), pk2(sqn[2], sqn[3]));

        f32x4 acc[16];
        bf16x8 B[4][2];

        // ---- phi_e L0 via MFMA: [W0a | I] @ [sqn | Bj] + Bi ----
        {
            const ushort_t* bjr = bjb + (size_t)jbase * 64;
            bf16x8 Bk[4][3];
            #pragma unroll
            for (int pt = 0; pt < 4; ++pt) {
                uint2 s = *(const uint2*)(sq + (pt*16 + ml) * 4);
                B8U u0;
                u0.u = (q == 0) ? make_uint4(s.x, s.y, 0u, 0u) : make_uint4(0u, 0u, 0u, 0u);
                Bk[pt][0] = u0.v;
                Bk[pt][1] = *(const bf16x8*)(bjr + (pt*16 + ml) * 64 + q*8);
                Bk[pt][2] = *(const bf16x8*)(bjr + (pt*16 + ml) * 64 + 32 + q*8);
            }
            #pragma unroll
            for (int t = 0; t < 16; ++t) acc[t] = f32x4{0.f, 0.f, 0.f, 0.f};
            #pragma unroll
            for (int mt = 0; mt < 4; ++mt) {
                #pragma unroll
                for (int kt = 0; kt < 3; ++kt) {
                    bf16x8 af = *(const bf16x8*)(l0a + (mt*16 + ml) * 96 + kt*32 + q*8);
                    #pragma unroll
                    for (int pt = 0; pt < 4; ++pt)
                        acc[mt*4 + pt] = __builtin_amdgcn_mfma_f32_16x16x32_bf16(af, Bk[pt][kt], acc[mt*4 + pt], 0, 0, 0);
                }
            }
            ep_silu4<false>(yb, ml, q, acc, bi4, nullptr);    // y0
        }

        // ---- phi_e L1: m = silu(y0 @ W1 + b1); capture packed m ----
        uint2 mpk[16];
        load_bfrags(yb, ml, q, B);
        #pragma unroll
        for (int t = 0; t < 16; ++t) acc[t] = f32x4{0.f, 0.f, 0.f, 0.f};
        gemmG<4>(wg + 0, ml, q, B, acc);
        ep_silu4<true>(yb, ml, q, acc, b_l1, mpk);

        // ---- phi_x L0 + phi_inf ----
        load_bfrags(yb, ml, q, B);
        f32x4 accI[4];
        #pragma unroll
        for (int t = 0; t < 16; ++t) acc[t] = f32x4{0.f, 0.f, 0.f, 0.f};
        #pragma unroll
        for (int t = 0; t < 4; ++t) accI[t] = f32x4{0.f, 0.f, 0.f, 0.f};
        gemmG<4>(wg + 64*64, ml, q, B, acc);
        gemmG<1>(wg + 128*64, ml, q, B, accI);

        if (q == 0) {
            #pragma unroll
            for (int pt = 0; pt < 4; ++pt) sbuf[wv][pt*16 + ml] = accI[pt][0] + binf;
        }
        {
            float sv = sbuf[wv][lane];
            float ea = (jg == i) ? 0.0f : 1.0f / (1.0f + __expf(-sv));
            sbuf[wv][lane] = ea;
        }

        // ---- m_i in registers: macc[n'-slot] += e_p * m[p][n'] ----
        {
            float e4[4];
            #pragma unroll
            for (int pt = 0; pt < 4; ++pt) e4[pt] = sbuf[wv][pt*16 + ml];
            #pragma unroll
            for (int mt = 0; mt < 4; ++mt) {
                #pragma unroll
                for (int pt = 0; pt < 4; ++pt) {
                    uint2 w = mpk[mt*4 + pt];
                    float ev = e4[pt];
                    macc[mt*4 + 0] += ev * __uint_as_float(w.x << 16);
                    macc[mt*4 + 1] += ev * __uint_as_float(w.x & 0xFFFF0000u);
                    macc[mt*4 + 2] += ev * __uint_as_float(w.y << 16);
                    macc[mt*4 + 3] += ev * __uint_as_float(w.y & 0xFFFF0000u);
                }
            }
        }

        ep_silu4<false>(yb, ml, q, acc, b_x0, nullptr);   // y1 (m dead in yb)

        // ---- phi_x L1 ----
        load_bfrags(yb, ml, q, B);
        #pragma unroll
        for (int t = 0; t < 16; ++t) acc[t] = f32x4{0.f, 0.f, 0.f, 0.f};
        gemmG<4>(wg + 144*64, ml, q, B, acc);
        ep_silu4<false>(yb, ml, q, acc, b_x1, nullptr);   // y2

        // ---- phi_x L2 (64 -> 4) ----
        load_bfrags(yb, ml, q, B);
        f32x4 acc2[4];
        #pragma unroll
        for (int t = 0; t < 4; ++t) acc2[t] = f32x4{0.f, 0.f, 0.f, 0.f};
        gemmG<1>(wg + 208*64, ml, q, B, acc2);
        if (q == 0) {
            #pragma unroll
            for (int pt = 0; pt < 4; ++pt) {
                float4 pv = make_float4(acc2[pt][0] + b_x2.x, acc2[pt][1] + b_x2.y,
                                        acc2[pt][2] + b_x2.z, acc2[pt][3] + b_x2.w);
                *(float4*)(pbuf[wv] + (pt*16 + ml) * 4) = pv;
            }
        }

        // ---- shift contributions (lane = p) ----
        {
            float4 pv = *(const float4*)(pbuf[wv] + lane * 4);
            float pvh[4] = {pv.x, pv.y, pv.z, pv.w};
            float mask = (jg == i) ? 0.0f : 1.0f;
            #pragma unroll
            for (int hh = 0; hh < 4; ++hh) {
                float nsq = (sqn[hh] == 0.0f) ? 1.0f : sqn[hh];
                float inv = mask * pvh[hh] / (sqrtf(nsq) + 1.0f);
                #pragma unroll
                for (int d = 0; d < 3; ++d)
                    sacc[hh*3 + d] += dx[hh*3 + d] * inv;
            }
        }
    }

    // m_i: reduce macc over ml within 16-lane groups (n' is fixed per q)
    #pragma unroll
    for (int s = 0; s < 16; ++s) {
        float v = macc[s];
        v += __shfl_xor(v, 1, 64);
        v += __shfl_xor(v, 2, 64);
        v += __shfl_xor(v, 4, 64);
        v += __shfl_xor(v, 8, 64);
        macc[s] = v;
    }
    if (ml == 0) {
        #pragma unroll
        for (int mt = 0; mt < 4; ++mt)
            #pragma unroll
            for (int r = 0; r < 4; ++r)
                redm[wv][mt*16 + q*4 + r] = macc[mt*4 + r];
    }

    // shift: one butterfly at the end
    #pragma unroll
    for (int t = 0; t < 12; ++t) {
        float v = sacc[t];
        v += __shfl_xor(v, 1, 64);
        v += __shfl_xor(v, 2, 64);
        v += __shfl_xor(v, 4, 64);
        v += __shfl_xor(v, 8, 64);
        v += __shfl_xor(v, 16, 64);
        v += __shfl_xor(v, 32, 64);
        sacc[t] = v;
    }
    if (lane == 0) {
        #pragma unroll
        for (int t = 0; t < 12; ++t) reds[wv][t] = sacc[t];
    }
    __syncthreads();

    if (wv == 0) {
        float mi = (redm[0][lane] + redm[1][lane] + redm[2][lane] + redm[3][lane])
                   * (1.0f / sqrtf(767.0f));
        inbuf[lane] = mi;

        if (lane < 12) {
            float sh = reds[0][lane] + reds[1][lane] + reds[2][lane] + reds[3][lane];
            out[i*12 + lane] = x[i*12 + lane] + sh * (1.0f / 767.0f);
        }

        float a = hb0[lane];
        #pragma unroll 8
        for (int k = 0; k < 128; ++k) a += inbuf[k] * hw0[k*64 + lane];
        zbuf[lane] = silu_f(a);

        a = hb1[lane];
        #pragma unroll 8
        for (int k = 0; k < 64; ++k) a += zbuf[k] * hw1[k*64 + lane];
        zbuf[lane] = silu_f(a);

        a = hb2[lane];
        #pragma unroll 8
        for (int k = 0; k < 64; ++k) a += zbuf[k] * hw2[k*64 + lane];
        out[9216 + i*64 + lane] = h[i*64 + lane] + a;
    }
}

extern "C" void kernel_launch(void* const* d_in, const int* in_sizes, int n_in,
                              void* d_out, int out_size, void* d_ws, size_t ws_size,
                              hipStream_t stream) {
    const float* x    = (const float*)d_in[0];
    const float* h    = (const float*)d_in[1];
    const float* ew0  = (const float*)d_in[2];
    const float* eb0  = (const float*)d_in[3];
    const float* ew1  = (const float*)d_in[4];
    const float* eb1  = (const float*)d_in[5];
    const float* infw = (const float*)d_in[6];
    const float* infb = (const float*)d_in[7];
    const float* xw0  = (const float*)d_in[8];
    const float* xb0  = (const float*)d_in[9];
    const float* xw1  = (const float*)d_in[10];
    const float* xb1  = (const float*)d_in[11];
    const float* xw2  = (const float*)d_in[12];
    const float* xb2  = (const float*)d_in[13];
    const float* hw0  = (const float*)d_in[14];
    const float* hb0  = (const float*)d_in[15];
    const float* hw1  = (const float*)d_in[16];
    const float* hb1  = (const float*)d_in[17];
    const float* hw2  = (const float*)d_in[18];
    const float* hb2  = (const float*)d_in[19];

    float* ws  = (float*)d_ws;
    float* out = (float*)d_out;

    prep_kernel<<<809, 64, 0, stream>>>(x, h, ew0, eb0, ew1, eb1, infw, infb,
                                        xw0, xb0, xw1, xb1, xw2, xb2, ws);
    egcl_kernel<<<768, 256, 0, stream>>>(x, h, hw0, hb0, hw1, hb1, hw2, hb2, ws, out);
}

// Round 5
// 300.209 us; speedup vs baseline: 1.3852x; 1.3852x over previous
//
#include <hip/hip_runtime.h>
#include <hip/hip_bf16.h>
#include <math.h>

// N=768, H=4, D=3, HDIM=64, HID=64. e_in[i,j] = [sqn(4) | hc[j](80) | hc[i](80)]
// z0 = sqn@W0a + Bj[j] + Bi[i]  (Bi includes b0 and the hc[i] half).
// A = weights (rows = output features) read straight from GLOBAL (28 KB image,
// L2-resident, shared by all blocks); B = activations in per-wave LDS [p][k]
// stride 72. D[row=n'][col=p] -> packed b64 epilogue stores; next layer b128 reads.
// LDS ~44 KB -> 3 blocks/CU.
//
// ws layout (float offsets):
#define WS_BJ    0         // Bj [768][64] f32
#define WS_BI    49152     // Bi [768][64] f32
#define WS_W0AT  98304     // W0a^T [64][4] f32
#define WS_BIAS  98560     // [224] f32: eb1@0, xb0@64, infb@128, 0, xb1@144, xb2@208, 0
#define WS_WG    98784     // bf16 [224 rows][64]: W1^T@0, X0^T@64, infw@128, 0, X1^T@144, X2^T@208, 0

typedef unsigned short ushort_t;
typedef __attribute__((ext_vector_type(8))) __bf16 bf16x8;
typedef __attribute__((ext_vector_type(4))) float f32x4;

__device__ __forceinline__ float silu_f(float v) { return v / (1.0f + __expf(-v)); }

__device__ __forceinline__ ushort_t bf16r(float f) {
    unsigned u = __float_as_uint(f);
    u += 0x7FFFu + ((u >> 16) & 1u);
    return (ushort_t)(u >> 16);
}
__device__ __forceinline__ float bf2f(ushort_t s) { return __uint_as_float(((unsigned)s) << 16); }

__device__ __forceinline__ unsigned pk2(float a, float b) {
    __hip_bfloat162 t = __float22bfloat162_rn(make_float2(a, b));
    return *reinterpret_cast<unsigned*>(&t);
}

// ---------------- prep ----------------
__global__ __launch_bounds__(64) void prep_kernel(
    const float* __restrict__ x, const float* __restrict__ h,
    const float* __restrict__ ew0, const float* __restrict__ eb0,
    const float* __restrict__ ew1, const float* __restrict__ eb1,
    const float* __restrict__ infw, const float* __restrict__ infb,
    const float* __restrict__ xw0, const float* __restrict__ xb0,
    const float* __restrict__ xw1, const float* __restrict__ xb1,
    const float* __restrict__ xw2, const float* __restrict__ xb2,
    float* __restrict__ ws)
{
    const int blk = blockIdx.x, t = threadIdx.x;
    if (blk < 768) {
        __shared__ float hcs[80];
        const int m = blk;
        hcs[t] = h[m * 64 + t];
        if (t < 16) {
            int i2 = t >> 2, j2 = t & 3;
            float d0 = x[m*12 + j2*3 + 0] - x[m*12 + i2*3 + 0];
            float d1 = x[m*12 + j2*3 + 1] - x[m*12 + i2*3 + 1];
            float d2 = x[m*12 + j2*3 + 2] - x[m*12 + i2*3 + 2];
            hcs[64 + t] = d0*d0 + d1*d1 + d2*d2;
        }
        __syncthreads();
        float bj = 0.0f, bi = eb0[t];
        #pragma unroll 4
        for (int k = 0; k < 80; ++k) {
            float hv = hcs[k];
            bj += hv * ew0[(4 + k) * 64 + t];
            bi += hv * ew0[(84 + k) * 64 + t];
        }
        ws[WS_BJ + m * 64 + t] = bj;
        ws[WS_BI + m * 64 + t] = bi;
    } else if (blk == 768) {
        #pragma unroll
        for (int hh = 0; hh < 4; ++hh) ws[WS_W0AT + t * 4 + hh] = ew0[hh * 64 + t];
        #pragma unroll
        for (int u = 0; u < 4; ++u) {
            int idx = u * 64 + t;
            if (idx < 224) {
                float v;
                if (idx < 64)        v = eb1[idx];
                else if (idx < 128)  v = xb0[idx - 64];
                else if (idx == 128) v = infb[0];
                else if (idx < 144)  v = 0.0f;
                else if (idx < 208)  v = xb1[idx - 144];
                else if (idx < 212)  v = xb2[idx - 208];
                else                 v = 0.0f;
                ws[WS_BIAS + idx] = v;
            }
        }
    } else {
        ushort_t* wg = (ushort_t*)(ws + WS_WG);
        #pragma unroll 1
        for (int u = 0; u < 8; ++u) {
            int e = (blk - 769) * 512 + u * 64 + t;    // < 14336
            int r = e >> 6, k = e & 63;
            float v;
            if (r < 64)        v = ew1[k * 64 + r];
            else if (r < 128)  v = xw0[k * 64 + (r - 64)];
            else if (r == 128) v = infw[k];
            else if (r < 144)  v = 0.0f;
            else if (r < 208)  v = xw1[k * 64 + (r - 144)];
            else if (r < 212)  v = xw2[k * 4 + (r - 208)];
            else               v = 0.0f;
            wg[e] = bf16r(v);
        }
    }
}

// B-frags from per-wave LDS activations [p][k], stride 72
__device__ __forceinline__ void load_bfrags(const ushort_t* yb, int ml, int q, bf16x8 B[4][2]) {
    #pragma unroll
    for (int pt = 0; pt < 4; ++pt)
        #pragma unroll
        for (int kt = 0; kt < 2; ++kt)
            B[pt][kt] = *(const bf16x8*)(yb + (pt*16 + ml) * 72 + kt*32 + q*8);
}

// A-frags from GLOBAL weight image (rows x 64, row-major, L2-hot)
template<int NMT>
__device__ __forceinline__ void gemmG(const ushort_t* __restrict__ wg, int ml, int q,
                                      const bf16x8 B[4][2], f32x4* acc) {
    #pragma unroll
    for (int mt = 0; mt < NMT; ++mt) {
        #pragma unroll
        for (int kt = 0; kt < 2; ++kt) {
            bf16x8 af = *(const bf16x8*)(wg + (mt*16 + ml) * 64 + kt*32 + q*8);
            #pragma unroll
            for (int pt = 0; pt < 4; ++pt)
                acc[mt*4 + pt] = __builtin_amdgcn_mfma_f32_16x16x32_bf16(af, B[pt][kt], acc[mt*4 + pt], 0, 0, 0);
        }
    }
}

// epilogue: y[p][n'] = bf16(silu(acc + bias)); bias loaded per call (L1-hit), not held
__device__ __forceinline__ void ep_silu4(ushort_t* yb, int ml, int q,
                                         const f32x4* acc, const float* __restrict__ bias) {
    #pragma unroll
    for (int mt = 0; mt < 4; ++mt) {
        float4 bv = *(const float4*)(bias + mt*16 + q*4);
        #pragma unroll
        for (int pt = 0; pt < 4; ++pt) {
            f32x4 a = acc[mt*4 + pt];
            uint2 w = make_uint2(pk2(silu_f(a[0] + bv.x), silu_f(a[1] + bv.y)),
                                 pk2(silu_f(a[2] + bv.z), silu_f(a[3] + bv.w)));
            *(uint2*)(yb + (pt*16 + ml) * 72 + mt*16 + q*4) = w;
        }
    }
}

// ---------------- main fused kernel: one block per row i ----------------
__global__ __launch_bounds__(256, 3) void egcl_kernel(
    const float* __restrict__ x, const float* __restrict__ h,
    const float* __restrict__ hw0, const float* __restrict__ hb0,
    const float* __restrict__ hw1, const float* __restrict__ hb1,
    const float* __restrict__ hw2, const float* __restrict__ hb2,
    const float* __restrict__ ws, float* __restrict__ out)
{
    __shared__ ushort_t ybuf[4][4608];    // per-wave acts [64 p][72], 9 KB each
    __shared__ float sbuf[4][64];
    __shared__ float pbuf[4][256];
    __shared__ float redm[4][64];
    __shared__ float reds[4][12];
    __shared__ float inbuf[128];
    __shared__ float zbuf[64];

    const int i = blockIdx.x, tid = threadIdx.x;
    const int wv = tid >> 6, lane = tid & 63;
    const int ml = lane & 15, q = lane >> 4;

    const ushort_t* wg = (const ushort_t*)(ws + WS_WG);
    const float* bias  = ws + WS_BIAS;

    if (wv == 1) inbuf[64 + lane] = h[i * 64 + lane];

    float xi[12];
    #pragma unroll
    for (int t = 0; t < 12; ++t) xi[t] = x[i * 12 + t];

    const float* Bi   = ws + WS_BI + i * 64;   // uniform -> s_load
    const float* w0at = ws + WS_W0AT;          // uniform -> s_load
    ushort_t* yb = ybuf[wv];

    float macc = 0.0f;
    float sacc[12];
    #pragma unroll
    for (int t = 0; t < 12; ++t) sacc[t] = 0.0f;

    #pragma unroll 1
    for (int it = 0; it < 3; ++it) {
        const int jg = it * 256 + wv * 64 + lane;

        float dx[12];
        {
            const float4* xp = (const float4*)(x + jg * 12);
            float4 a = xp[0], b = xp[1], c = xp[2];
            dx[0]=a.x-xi[0]; dx[1]=a.y-xi[1]; dx[2]=a.z-xi[2];  dx[3]=a.w-xi[3];
            dx[4]=b.x-xi[4]; dx[5]=b.y-xi[5]; dx[6]=b.z-xi[6];  dx[7]=b.w-xi[7];
            dx[8]=c.x-xi[8]; dx[9]=c.y-xi[9]; dx[10]=c.z-xi[10];dx[11]=c.w-xi[11];
        }
        float sqn[4];
        #pragma unroll
        for (int hh = 0; hh < 4; ++hh)
            sqn[hh] = dx[hh*3]*dx[hh*3] + dx[hh*3+1]*dx[hh*3+1] + dx[hh*3+2]*dx[hh*3+2];

        // ---- phi_e L0 (VALU, K=4 + Bi + Bj); write y0[p=lane][k] b128-packed ----
        {
            const float* Bj = ws + WS_BJ + jg * 64;
            #pragma unroll
            for (int b = 0; b < 8; ++b) {
                float4 A = *(const float4*)(Bj + b*8);
                float4 Bv = *(const float4*)(Bj + b*8 + 4);
                float z[8] = {A.x, A.y, A.z, A.w, Bv.x, Bv.y, Bv.z, Bv.w};
                #pragma unroll
                for (int u = 0; u < 8; ++u) {
                    int l = b*8 + u;
                    float v = Bi[l] + z[u]
                            + sqn[0]*w0at[l*4+0] + sqn[1]*w0at[l*4+1]
                            + sqn[2]*w0at[l*4+2] + sqn[3]*w0at[l*4+3];
                    z[u] = silu_f(v);
                }
                uint4 pkv = make_uint4(pk2(z[0],z[1]), pk2(z[2],z[3]),
                                       pk2(z[4],z[5]), pk2(z[6],z[7]));
                *(uint4*)(yb + lane * 72 + b*8) = pkv;
            }
        }

        bf16x8 B[4][2];
        f32x4 acc[16];

        // ---- phi_e L1: m = silu(y0 @ W1 + b1) ----
        load_bfrags(yb, ml, q, B);
        #pragma unroll
        for (int t = 0; t < 16; ++t) acc[t] = f32x4{0.f, 0.f, 0.f, 0.f};
        gemmG<4>(wg + 0, ml, q, B, acc);
        ep_silu4(yb, ml, q, acc, bias + 0);

        // ---- phi_x L0 + phi_inf (B = m) ----
        load_bfrags(yb, ml, q, B);
        f32x4 accI[4];
        #pragma unroll
        for (int t = 0; t < 16; ++t) acc[t] = f32x4{0.f, 0.f, 0.f, 0.f};
        #pragma unroll
        for (int t = 0; t < 4; ++t) accI[t] = f32x4{0.f, 0.f, 0.f, 0.f};
        gemmG<4>(wg + 64*64, ml, q, B, acc);
        gemmG<1>(wg + 128*64, ml, q, B, accI);

        // s_inf -> e (lane = p)
        if (q == 0) {
            #pragma unroll
            for (int pt = 0; pt < 4; ++pt) sbuf[wv][pt*16 + ml] = accI[pt][0] + bias[128];
        }
        {
            float sv = sbuf[wv][lane];
            float ea = (jg == i) ? 0.0f : 1.0f / (1.0f + __expf(-sv));
            sbuf[wv][lane] = ea;
        }

        // ---- m_i partial: lane=l sums e_p * m[p][l] (m still in yb) ----
        #pragma unroll 8
        for (int j2 = 0; j2 < 64; ++j2) {
            float ev = sbuf[wv][j2];
            macc += ev * bf2f(yb[j2 * 72 + lane]);
        }

        ep_silu4(yb, ml, q, acc, bias + 64);    // y1 -> yb (m dead)

        // ---- phi_x L1 ----
        load_bfrags(yb, ml, q, B);
        #pragma unroll
        for (int t = 0; t < 16; ++t) acc[t] = f32x4{0.f, 0.f, 0.f, 0.f};
        gemmG<4>(wg + 144*64, ml, q, B, acc);
        ep_silu4(yb, ml, q, acc, bias + 144);   // y2 -> yb

        // ---- phi_x L2 (64 -> 4) ----
        load_bfrags(yb, ml, q, B);
        f32x4 acc2[4];
        #pragma unroll
        for (int t = 0; t < 4; ++t) acc2[t] = f32x4{0.f, 0.f, 0.f, 0.f};
        gemmG<1>(wg + 208*64, ml, q, B, acc2);
        if (q == 0) {
            float4 bx2 = *(const float4*)(bias + 208);
            #pragma unroll
            for (int pt = 0; pt < 4; ++pt) {
                float4 pv = make_float4(acc2[pt][0] + bx2.x, acc2[pt][1] + bx2.y,
                                        acc2[pt][2] + bx2.z, acc2[pt][3] + bx2.w);
                *(float4*)(pbuf[wv] + (pt*16 + ml) * 4) = pv;
            }
        }

        // ---- shift contributions (lane = p) ----
        {
            float4 pv = *(const float4*)(pbuf[wv] + lane * 4);
            float pvh[4] = {pv.x, pv.y, pv.z, pv.w};
            float mask = (jg == i) ? 0.0f : 1.0f;
            #pragma unroll
            for (int hh = 0; hh < 4; ++hh) {
                float nsq = (sqn[hh] == 0.0f) ? 1.0f : sqn[hh];
                float inv = mask * pvh[hh] / (sqrtf(nsq) + 1.0f);
                #pragma unroll
                for (int d = 0; d < 3; ++d)
                    sacc[hh*3 + d] += dx[hh*3 + d] * inv;
            }
        }
    }

    // shift: one butterfly at the end
    #pragma unroll
    for (int t = 0; t < 12; ++t) {
        float v = sacc[t];
        v += __shfl_xor(v, 1, 64);
        v += __shfl_xor(v, 2, 64);
        v += __shfl_xor(v, 4, 64);
        v += __shfl_xor(v, 8, 64);
        v += __shfl_xor(v, 16, 64);
        v += __shfl_xor(v, 32, 64);
        sacc[t] = v;
    }

    redm[wv][lane] = macc;
    if (lane == 0) {
        #pragma unroll
        for (int t = 0; t < 12; ++t) reds[wv][t] = sacc[t];
    }
    __syncthreads();

    if (wv == 0) {
        float mi = (redm[0][lane] + redm[1][lane] + redm[2][lane] + redm[3][lane])
                   * (1.0f / sqrtf(767.0f));
        inbuf[lane] = mi;

        if (lane < 12) {
            float sh = reds[0][lane] + reds[1][lane] + reds[2][lane] + reds[3][lane];
            out[i*12 + lane] = x[i*12 + lane] + sh * (1.0f / 767.0f);
        }

        float a = hb0[lane];
        #pragma unroll 8
        for (int k = 0; k < 128; ++k) a += inbuf[k] * hw0[k*64 + lane];
        zbuf[lane] = silu_f(a);

        a = hb1[lane];
        #pragma unroll 8
        for (int k = 0; k < 64; ++k) a += zbuf[k] * hw1[k*64 + lane];
        zbuf[lane] = silu_f(a);

        a = hb2[lane];
        #pragma unroll 8
        for (int k = 0; k < 64; ++k) a += zbuf[k] * hw2[k*64 + lane];
        out[9216 + i*64 + lane] = h[i*64 + lane] + a;
    }
}

extern "C" void kernel_launch(void* const* d_in, const int* in_sizes, int n_in,
                              void* d_out, int out_size, void* d_ws, size_t ws_size,
                              hipStream_t stream) {
    const float* x    = (const float*)d_in[0];
    const float* h    = (const float*)d_in[1];
    const float* ew0  = (const float*)d_in[2];
    const float* eb0  = (const float*)d_in[3];
    const float* ew1  = (const float*)d_in[4];
    const float* eb1  = (const float*)d_in[5];
    const float* infw = (const float*)d_in[6];
    const float* infb = (const float*)d_in[7];
    const float* xw0  = (const float*)d_in[8];
    const float* xb0  = (const float*)d_in[9];
    const float* xw1  = (const float*)d_in[10];
    const float* xb1  = (const float*)d_in[11];
    const float* xw2  = (const float*)d_in[12];
    const float* xb2  = (const float*)d_in[13];
    const float* hw0  = (const float*)d_in[14];
    const float* hb0  = (const float*)d_in[15];
    const float* hw1  = (const float*)d_in[16];
    const float* hb1  = (const float*)d_in[17];
    const float* hw2  = (const float*)d_in[18];
    const float* hb2  = (const float*)d_in[19];

    float* ws  = (float*)d_ws;
    float* out = (float*)d_out;

    prep_kernel<<<797, 64, 0, stream>>>(x, h, ew0, eb0, ew1, eb1, infw, infb,
                                        xw0, xb0, xw1, xb1, xw2, xb2, ws);
    egcl_kernel<<<768, 256, 0, stream>>>(x, h, hw0, hb0, hw1, hb1, hw2, hb2, ws, out);
}

// Round 6
// 267.524 us; speedup vs baseline: 1.5545x; 1.1222x over previous
//
#include <hip/hip_runtime.h>
#include <hip/hip_bf16.h>
#include <math.h>

// N=768, H=4, D=3, HDIM=64, HID=64. e_in[i,j] = [sqn(4) | hc[j](80) | hc[i](80)]
// z0 = sqn@W0a + Bj[j] + Bi[i]  (Bi includes b0 and the hc[i] half).
// A = weights (rows = output features) read straight from GLOBAL (28 KB image,
// L2-resident, shared by all blocks); B = activations in per-wave LDS [p][k]
// stride 72. D[row=n'][col=p] -> packed b64 epilogue stores; next layer b128 reads.
// LDS ~44 KB. launch_bounds(256,2): (256,3) made the allocator target ~84 VGPR
// and spill ~450 MB/launch to scratch (rounds 4-5) — (256,2) is spill-free.
//
// ws layout (float offsets):
#define WS_BJ    0         // Bj [768][64] f32
#define WS_BI    49152     // Bi [768][64] f32
#define WS_W0AT  98304     // W0a^T [64][4] f32
#define WS_BIAS  98560     // [224] f32: eb1@0, xb0@64, infb@128, 0, xb1@144, xb2@208, 0
#define WS_WG    98784     // bf16 [224 rows][64]: W1^T@0, X0^T@64, infw@128, 0, X1^T@144, X2^T@208, 0

typedef unsigned short ushort_t;
typedef __attribute__((ext_vector_type(8))) __bf16 bf16x8;
typedef __attribute__((ext_vector_type(4))) float f32x4;

__device__ __forceinline__ float silu_f(float v) { return v / (1.0f + __expf(-v)); }

__device__ __forceinline__ ushort_t bf16r(float f) {
    unsigned u = __float_as_uint(f);
    u += 0x7FFFu + ((u >> 16) & 1u);
    return (ushort_t)(u >> 16);
}
__device__ __forceinline__ float bf2f(ushort_t s) { return __uint_as_float(((unsigned)s) << 16); }

__device__ __forceinline__ unsigned pk2(float a, float b) {
    __hip_bfloat162 t = __float22bfloat162_rn(make_float2(a, b));
    return *reinterpret_cast<unsigned*>(&t);
}

// ---------------- prep ----------------
__global__ __launch_bounds__(64) void prep_kernel(
    const float* __restrict__ x, const float* __restrict__ h,
    const float* __restrict__ ew0, const float* __restrict__ eb0,
    const float* __restrict__ ew1, const float* __restrict__ eb1,
    const float* __restrict__ infw, const float* __restrict__ infb,
    const float* __restrict__ xw0, const float* __restrict__ xb0,
    const float* __restrict__ xw1, const float* __restrict__ xb1,
    const float* __restrict__ xw2, const float* __restrict__ xb2,
    float* __restrict__ ws)
{
    const int blk = blockIdx.x, t = threadIdx.x;
    if (blk < 768) {
        __shared__ float hcs[80];
        const int m = blk;
        hcs[t] = h[m * 64 + t];
        if (t < 16) {
            int i2 = t >> 2, j2 = t & 3;
            float d0 = x[m*12 + j2*3 + 0] - x[m*12 + i2*3 + 0];
            float d1 = x[m*12 + j2*3 + 1] - x[m*12 + i2*3 + 1];
            float d2 = x[m*12 + j2*3 + 2] - x[m*12 + i2*3 + 2];
            hcs[64 + t] = d0*d0 + d1*d1 + d2*d2;
        }
        __syncthreads();
        float bj = 0.0f, bi = eb0[t];
        #pragma unroll 4
        for (int k = 0; k < 80; ++k) {
            float hv = hcs[k];
            bj += hv * ew0[(4 + k) * 64 + t];
            bi += hv * ew0[(84 + k) * 64 + t];
        }
        ws[WS_BJ + m * 64 + t] = bj;
        ws[WS_BI + m * 64 + t] = bi;
    } else if (blk == 768) {
        #pragma unroll
        for (int hh = 0; hh < 4; ++hh) ws[WS_W0AT + t * 4 + hh] = ew0[hh * 64 + t];
        #pragma unroll
        for (int u = 0; u < 4; ++u) {
            int idx = u * 64 + t;
            if (idx < 224) {
                float v;
                if (idx < 64)        v = eb1[idx];
                else if (idx < 128)  v = xb0[idx - 64];
                else if (idx == 128) v = infb[0];
                else if (idx < 144)  v = 0.0f;
                else if (idx < 208)  v = xb1[idx - 144];
                else if (idx < 212)  v = xb2[idx - 208];
                else                 v = 0.0f;
                ws[WS_BIAS + idx] = v;
            }
        }
    } else {
        ushort_t* wg = (ushort_t*)(ws + WS_WG);
        #pragma unroll 1
        for (int u = 0; u < 8; ++u) {
            int e = (blk - 769) * 512 + u * 64 + t;    // < 14336
            int r = e >> 6, k = e & 63;
            float v;
            if (r < 64)        v = ew1[k * 64 + r];
            else if (r < 128)  v = xw0[k * 64 + (r - 64)];
            else if (r == 128) v = infw[k];
            else if (r < 144)  v = 0.0f;
            else if (r < 208)  v = xw1[k * 64 + (r - 144)];
            else if (r < 212)  v = xw2[k * 4 + (r - 208)];
            else               v = 0.0f;
            wg[e] = bf16r(v);
        }
    }
}

// B-frags from per-wave LDS activations [p][k], stride 72
__device__ __forceinline__ void load_bfrags(const ushort_t* yb, int ml, int q, bf16x8 B[4][2]) {
    #pragma unroll
    for (int pt = 0; pt < 4; ++pt)
        #pragma unroll
        for (int kt = 0; kt < 2; ++kt)
            B[pt][kt] = *(const bf16x8*)(yb + (pt*16 + ml) * 72 + kt*32 + q*8);
}

// A-frags from GLOBAL weight image (rows x 64, row-major, L2-hot)
template<int NMT>
__device__ __forceinline__ void gemmG(const ushort_t* __restrict__ wg, int ml, int q,
                                      const bf16x8 B[4][2], f32x4* acc) {
    #pragma unroll
    for (int mt = 0; mt < NMT; ++mt) {
        #pragma unroll
        for (int kt = 0; kt < 2; ++kt) {
            bf16x8 af = *(const bf16x8*)(wg + (mt*16 + ml) * 64 + kt*32 + q*8);
            #pragma unroll
            for (int pt = 0; pt < 4; ++pt)
                acc[mt*4 + pt] = __builtin_amdgcn_mfma_f32_16x16x32_bf16(af, B[pt][kt], acc[mt*4 + pt], 0, 0, 0);
        }
    }
}

// epilogue: y[p][n'] = bf16(silu(acc + bias)); bias loaded per call (L1-hit), not held
__device__ __forceinline__ void ep_silu4(ushort_t* yb, int ml, int q,
                                         const f32x4* acc, const float* __restrict__ bias) {
    #pragma unroll
    for (int mt = 0; mt < 4; ++mt) {
        float4 bv = *(const float4*)(bias + mt*16 + q*4);
        #pragma unroll
        for (int pt = 0; pt < 4; ++pt) {
            f32x4 a = acc[mt*4 + pt];
            uint2 w = make_uint2(pk2(silu_f(a[0] + bv.x), silu_f(a[1] + bv.y)),
                                 pk2(silu_f(a[2] + bv.z), silu_f(a[3] + bv.w)));
            *(uint2*)(yb + (pt*16 + ml) * 72 + mt*16 + q*4) = w;
        }
    }
}

// ---------------- main fused kernel: one block per row i ----------------
__global__ __launch_bounds__(256, 2) void egcl_kernel(
    const float* __restrict__ x, const float* __restrict__ h,
    const float* __restrict__ hw0, const float* __restrict__ hb0,
    const float* __restrict__ hw1, const float* __restrict__ hb1,
    const float* __restrict__ hw2, const float* __restrict__ hb2,
    const float* __restrict__ ws, float* __restrict__ out)
{
    __shared__ ushort_t ybuf[4][4608];    // per-wave acts [64 p][72], 9 KB each
    __shared__ float sbuf[4][64];
    __shared__ float pbuf[4][256];
    __shared__ float redm[4][64];
    __shared__ float reds[4][12];
    __shared__ float inbuf[128];
    __shared__ float zbuf[64];

    const int i = blockIdx.x, tid = threadIdx.x;
    const int wv = tid >> 6, lane = tid & 63;
    const int ml = lane & 15, q = lane >> 4;

    const ushort_t* wg = (const ushort_t*)(ws + WS_WG);
    const float* bias  = ws + WS_BIAS;

    if (wv == 1) inbuf[64 + lane] = h[i * 64 + lane];

    float xi[12];
    #pragma unroll
    for (int t = 0; t < 12; ++t) xi[t] = x[i * 12 + t];

    const float* Bi   = ws + WS_BI + i * 64;   // uniform -> s_load
    const float* w0at = ws + WS_W0AT;          // uniform -> s_load
    ushort_t* yb = ybuf[wv];

    float macc = 0.0f;
    float sacc[12];
    #pragma unroll
    for (int t = 0; t < 12; ++t) sacc[t] = 0.0f;

    #pragma unroll 1
    for (int it = 0; it < 3; ++it) {
        const int jg = it * 256 + wv * 64 + lane;

        float dx[12];
        {
            const float4* xp = (const float4*)(x + jg * 12);
            float4 a = xp[0], b = xp[1], c = xp[2];
            dx[0]=a.x-xi[0]; dx[1]=a.y-xi[1]; dx[2]=a.z-xi[2];  dx[3]=a.w-xi[3];
            dx[4]=b.x-xi[4]; dx[5]=b.y-xi[5]; dx[6]=b.z-xi[6];  dx[7]=b.w-xi[7];
            dx[8]=c.x-xi[8]; dx[9]=c.y-xi[9]; dx[10]=c.z-xi[10];dx[11]=c.w-xi[11];
        }
        float sqn[4];
        #pragma unroll
        for (int hh = 0; hh < 4; ++hh)
            sqn[hh] = dx[hh*3]*dx[hh*3] + dx[hh*3+1]*dx[hh*3+1] + dx[hh*3+2]*dx[hh*3+2];

        // ---- phi_e L0 (VALU, K=4 + Bi + Bj); write y0[p=lane][k] b128-packed ----
        {
            const float* Bj = ws + WS_BJ + jg * 64;
            #pragma unroll
            for (int b = 0; b < 8; ++b) {
                float4 A = *(const float4*)(Bj + b*8);
                float4 Bv = *(const float4*)(Bj + b*8 + 4);
                float z[8] = {A.x, A.y, A.z, A.w, Bv.x, Bv.y, Bv.z, Bv.w};
                #pragma unroll
                for (int u = 0; u < 8; ++u) {
                    int l = b*8 + u;
                    float v = Bi[l] + z[u]
                            + sqn[0]*w0at[l*4+0] + sqn[1]*w0at[l*4+1]
                            + sqn[2]*w0at[l*4+2] + sqn[3]*w0at[l*4+3];
                    z[u] = silu_f(v);
                }
                uint4 pkv = make_uint4(pk2(z[0],z[1]), pk2(z[2],z[3]),
                                       pk2(z[4],z[5]), pk2(z[6],z[7]));
                *(uint4*)(yb + lane * 72 + b*8) = pkv;
            }
        }

        bf16x8 B[4][2];
        f32x4 acc[16];

        // ---- phi_e L1: m = silu(y0 @ W1 + b1) ----
        load_bfrags(yb, ml, q, B);
        #pragma unroll
        for (int t = 0; t < 16; ++t) acc[t] = f32x4{0.f, 0.f, 0.f, 0.f};
        gemmG<4>(wg + 0, ml, q, B, acc);
        ep_silu4(yb, ml, q, acc, bias + 0);

        // ---- phi_x L0 + phi_inf (B = m) ----
        load_bfrags(yb, ml, q, B);
        f32x4 accI[4];
        #pragma unroll
        for (int t = 0; t < 16; ++t) acc[t] = f32x4{0.f, 0.f, 0.f, 0.f};
        #pragma unroll
        for (int t = 0; t < 4; ++t) accI[t] = f32x4{0.f, 0.f, 0.f, 0.f};
        gemmG<4>(wg + 64*64, ml, q, B, acc);
        gemmG<1>(wg + 128*64, ml, q, B, accI);

        // s_inf -> e (lane = p)
        if (q == 0) {
            #pragma unroll
            for (int pt = 0; pt < 4; ++pt) sbuf[wv][pt*16 + ml] = accI[pt][0] + bias[128];
        }
        {
            float sv = sbuf[wv][lane];
            float ea = (jg == i) ? 0.0f : 1.0f / (1.0f + __expf(-sv));
            sbuf[wv][lane] = ea;
        }

        // ---- m_i partial: lane=l sums e_p * m[p][l] (m still in yb) ----
        #pragma unroll 8
        for (int j2 = 0; j2 < 64; ++j2) {
            float ev = sbuf[wv][j2];
            macc += ev * bf2f(yb[j2 * 72 + lane]);
        }

        ep_silu4(yb, ml, q, acc, bias + 64);    // y1 -> yb (m dead)

        // ---- phi_x L1 ----
        load_bfrags(yb, ml, q, B);
        #pragma unroll
        for (int t = 0; t < 16; ++t) acc[t] = f32x4{0.f, 0.f, 0.f, 0.f};
        gemmG<4>(wg + 144*64, ml, q, B, acc);
        ep_silu4(yb, ml, q, acc, bias + 144);   // y2 -> yb

        // ---- phi_x L2 (64 -> 4) ----
        load_bfrags(yb, ml, q, B);
        f32x4 acc2[4];
        #pragma unroll
        for (int t = 0; t < 4; ++t) acc2[t] = f32x4{0.f, 0.f, 0.f, 0.f};
        gemmG<1>(wg + 208*64, ml, q, B, acc2);
        if (q == 0) {
            float4 bx2 = *(const float4*)(bias + 208);
            #pragma unroll
            for (int pt = 0; pt < 4; ++pt) {
                float4 pv = make_float4(acc2[pt][0] + bx2.x, acc2[pt][1] + bx2.y,
                                        acc2[pt][2] + bx2.z, acc2[pt][3] + bx2.w);
                *(float4*)(pbuf[wv] + (pt*16 + ml) * 4) = pv;
            }
        }

        // ---- shift contributions (lane = p) ----
        {
            float4 pv = *(const float4*)(pbuf[wv] + lane * 4);
            float pvh[4] = {pv.x, pv.y, pv.z, pv.w};
            float mask = (jg == i) ? 0.0f : 1.0f;
            #pragma unroll
            for (int hh = 0; hh < 4; ++hh) {
                float nsq = (sqn[hh] == 0.0f) ? 1.0f : sqn[hh];
                float inv = mask * pvh[hh] / (sqrtf(nsq) + 1.0f);
                #pragma unroll
                for (int d = 0; d < 3; ++d)
                    sacc[hh*3 + d] += dx[hh*3 + d] * inv;
            }
        }
    }

    // shift: one butterfly at the end
    #pragma unroll
    for (int t = 0; t < 12; ++t) {
        float v = sacc[t];
        v += __shfl_xor(v, 1, 64);
        v += __shfl_xor(v, 2, 64);
        v += __shfl_xor(v, 4, 64);
        v += __shfl_xor(v, 8, 64);
        v += __shfl_xor(v, 16, 64);
        v += __shfl_xor(v, 32, 64);
        sacc[t] = v;
    }

    redm[wv][lane] = macc;
    if (lane == 0) {
        #pragma unroll
        for (int t = 0; t < 12; ++t) reds[wv][t] = sacc[t];
    }
    __syncthreads();

    if (wv == 0) {
        float mi = (redm[0][lane] + redm[1][lane] + redm[2][lane] + redm[3][lane])
                   * (1.0f / sqrtf(767.0f));
        inbuf[lane] = mi;

        if (lane < 12) {
            float sh = reds[0][lane] + reds[1][lane] + reds[2][lane] + reds[3][lane];
            out[i*12 + lane] = x[i*12 + lane] + sh * (1.0f / 767.0f);
        }

        float a = hb0[lane];
        #pragma unroll 8
        for (int k = 0; k < 128; ++k) a += inbuf[k] * hw0[k*64 + lane];
        zbuf[lane] = silu_f(a);

        a = hb1[lane];
        #pragma unroll 8
        for (int k = 0; k < 64; ++k) a += zbuf[k] * hw1[k*64 + lane];
        zbuf[lane] = silu_f(a);

        a = hb2[lane];
        #pragma unroll 8
        for (int k = 0; k < 64; ++k) a += zbuf[k] * hw2[k*64 + lane];
        out[9216 + i*64 + lane] = h[i*64 + lane] + a;
    }
}

extern "C" void kernel_launch(void* const* d_in, const int* in_sizes, int n_in,
                              void* d_out, int out_size, void* d_ws, size_t ws_size,
                              hipStream_t stream) {
    const float* x    = (const float*)d_in[0];
    const float* h    = (const float*)d_in[1];
    const float* ew0  = (const float*)d_in[2];
    const float* eb0  = (const float*)d_in[3];
    const float* ew1  = (const float*)d_in[4];
    const float* eb1  = (const float*)d_in[5];
    const float* infw = (const float*)d_in[6];
    const float* infb = (const float*)d_in[7];
    const float* xw0  = (const float*)d_in[8];
    const float* xb0  = (const float*)d_in[9];
    const float* xw1  = (const float*)d_in[10];
    const float* xb1  = (const float*)d_in[11];
    const float* xw2  = (const float*)d_in[12];
    const float* xb2  = (const float*)d_in[13];
    const float* hw0  = (const float*)d_in[14];
    const float* hb0  = (const float*)d_in[15];
    const float* hw1  = (const float*)d_in[16];
    const float* hb1  = (const float*)d_in[17];
    const float* hw2  = (const float*)d_in[18];
    const float* hb2  = (const float*)d_in[19];

    float* ws  = (float*)d_ws;
    float* out = (float*)d_out;

    prep_kernel<<<797, 64, 0, stream>>>(x, h, ew0, eb0, ew1, eb1, infw, infb,
                                        xw0, xb0, xw1, xb1, xw2, xb2, ws);
    egcl_kernel<<<768, 256, 0, stream>>>(x, h, hw0, hb0, hw1, hb1, hw2, hb2, ws, out);
}

// Round 7
// 230.822 us; speedup vs baseline: 1.8016x; 1.1590x over previous
//
#include <hip/hip_runtime.h>
#include <hip/hip_bf16.h>
#include <math.h>

// N=768, H=4, D=3, HDIM=64, HID=64. e_in[i,j] = [sqn(4) | hc[j](80) | hc[i](80)]
// z0 = sqn@W0a + Bj[j] + Bi[i]  (Bi includes b0 and the hc[i] half).
// A = weights from GLOBAL (28 KB, L2-hot); B = activations in per-wave LDS
// [p][k] stride 72. GEMMs processed in two mt-halves (acc[8] live) to keep
// peak VGPR < 128 (acc[16] spilled ~200 MB/launch in round 6).
// silu uses raw v_rcp_f32: precise f32 division was ~60% of VALU issue.
//
// ws layout (float offsets):
#define WS_BJ    0         // Bj [768][64] f32
#define WS_BI    49152     // Bi [768][64] f32
#define WS_W0AT  98304     // W0a^T [64][4] f32
#define WS_BIAS  98560     // [224] f32: eb1@0, xb0@64, infb@128, 0, xb1@144, xb2@208, 0
#define WS_WG    98784     // bf16 [224 rows][64]: W1^T@0, X0^T@64, infw@128, 0, X1^T@144, X2^T@208, 0

typedef unsigned short ushort_t;
typedef __attribute__((ext_vector_type(8))) __bf16 bf16x8;
typedef __attribute__((ext_vector_type(4))) float f32x4;

__device__ __forceinline__ float silu_f(float v) {
    return v * __builtin_amdgcn_rcpf(1.0f + __expf(-v));
}
__device__ __forceinline__ float sigm_f(float v) {
    return __builtin_amdgcn_rcpf(1.0f + __expf(-v));
}

__device__ __forceinline__ ushort_t bf16r(float f) {
    unsigned u = __float_as_uint(f);
    u += 0x7FFFu + ((u >> 16) & 1u);
    return (ushort_t)(u >> 16);
}
__device__ __forceinline__ float bf2f(ushort_t s) { return __uint_as_float(((unsigned)s) << 16); }

__device__ __forceinline__ unsigned pk2(float a, float b) {
    __hip_bfloat162 t = __float22bfloat162_rn(make_float2(a, b));
    return *reinterpret_cast<unsigned*>(&t);
}

// ---------------- prep ----------------
__global__ __launch_bounds__(64) void prep_kernel(
    const float* __restrict__ x, const float* __restrict__ h,
    const float* __restrict__ ew0, const float* __restrict__ eb0,
    const float* __restrict__ ew1, const float* __restrict__ eb1,
    const float* __restrict__ infw, const float* __restrict__ infb,
    const float* __restrict__ xw0, const float* __restrict__ xb0,
    const float* __restrict__ xw1, const float* __restrict__ xb1,
    const float* __restrict__ xw2, const float* __restrict__ xb2,
    float* __restrict__ ws)
{
    const int blk = blockIdx.x, t = threadIdx.x;
    if (blk < 768) {
        __shared__ float hcs[80];
        const int m = blk;
        hcs[t] = h[m * 64 + t];
        if (t < 16) {
            int i2 = t >> 2, j2 = t & 3;
            float d0 = x[m*12 + j2*3 + 0] - x[m*12 + i2*3 + 0];
            float d1 = x[m*12 + j2*3 + 1] - x[m*12 + i2*3 + 1];
            float d2 = x[m*12 + j2*3 + 2] - x[m*12 + i2*3 + 2];
            hcs[64 + t] = d0*d0 + d1*d1 + d2*d2;
        }
        __syncthreads();
        float bj = 0.0f, bi = eb0[t];
        #pragma unroll 4
        for (int k = 0; k < 80; ++k) {
            float hv = hcs[k];
            bj += hv * ew0[(4 + k) * 64 + t];
            bi += hv * ew0[(84 + k) * 64 + t];
        }
        ws[WS_BJ + m * 64 + t] = bj;
        ws[WS_BI + m * 64 + t] = bi;
    } else if (blk == 768) {
        #pragma unroll
        for (int hh = 0; hh < 4; ++hh) ws[WS_W0AT + t * 4 + hh] = ew0[hh * 64 + t];
        #pragma unroll
        for (int u = 0; u < 4; ++u) {
            int idx = u * 64 + t;
            if (idx < 224) {
                float v;
                if (idx < 64)        v = eb1[idx];
                else if (idx < 128)  v = xb0[idx - 64];
                else if (idx == 128) v = infb[0];
                else if (idx < 144)  v = 0.0f;
                else if (idx < 208)  v = xb1[idx - 144];
                else if (idx < 212)  v = xb2[idx - 208];
                else                 v = 0.0f;
                ws[WS_BIAS + idx] = v;
            }
        }
    } else {
        ushort_t* wg = (ushort_t*)(ws + WS_WG);
        #pragma unroll 1
        for (int u = 0; u < 8; ++u) {
            int e = (blk - 769) * 512 + u * 64 + t;    // < 14336
            int r = e >> 6, k = e & 63;
            float v;
            if (r < 64)        v = ew1[k * 64 + r];
            else if (r < 128)  v = xw0[k * 64 + (r - 64)];
            else if (r == 128) v = infw[k];
            else if (r < 144)  v = 0.0f;
            else if (r < 208)  v = xw1[k * 64 + (r - 144)];
            else if (r < 212)  v = xw2[k * 4 + (r - 208)];
            else               v = 0.0f;
            wg[e] = bf16r(v);
        }
    }
}

// B-frags from per-wave LDS activations [p][k], stride 72
__device__ __forceinline__ void load_bfrags(const ushort_t* yb, int ml, int q, bf16x8 B[4][2]) {
    #pragma unroll
    for (int pt = 0; pt < 4; ++pt)
        #pragma unroll
        for (int kt = 0; kt < 2; ++kt)
            B[pt][kt] = *(const bf16x8*)(yb + (pt*16 + ml) * 72 + kt*32 + q*8);
}

// A-frags from GLOBAL weight image (rows x 64, row-major, L2-hot).
// wg already offset to the mt-half's first row.
template<int NMT>
__device__ __forceinline__ void gemmG(const ushort_t* __restrict__ wg, int ml, int q,
                                      const bf16x8 B[4][2], f32x4* acc) {
    #pragma unroll
    for (int mt = 0; mt < NMT; ++mt) {
        #pragma unroll
        for (int kt = 0; kt < 2; ++kt) {
            bf16x8 af = *(const bf16x8*)(wg + (mt*16 + ml) * 64 + kt*32 + q*8);
            #pragma unroll
            for (int pt = 0; pt < 4; ++pt)
                acc[mt*4 + pt] = __builtin_amdgcn_mfma_f32_16x16x32_bf16(af, B[pt][kt], acc[mt*4 + pt], 0, 0, 0);
        }
    }
}

// epilogue for one mt-half (2 tiles): y[p][coff + n'] = bf16(silu(acc + bias))
__device__ __forceinline__ void ep_silu2(ushort_t* yb, int ml, int q,
                                         const f32x4* acc, const float* __restrict__ bias,
                                         int coff) {
    #pragma unroll
    for (int mt = 0; mt < 2; ++mt) {
        float4 bv = *(const float4*)(bias + coff + mt*16 + q*4);
        #pragma unroll
        for (int pt = 0; pt < 4; ++pt) {
            f32x4 a = acc[mt*4 + pt];
            uint2 w = make_uint2(pk2(silu_f(a[0] + bv.x), silu_f(a[1] + bv.y)),
                                 pk2(silu_f(a[2] + bv.z), silu_f(a[3] + bv.w)));
            *(uint2*)(yb + (pt*16 + ml) * 72 + coff + mt*16 + q*4) = w;
        }
    }
}

// one full 64x64 layer as two mt-halves (keeps peak acc regs at 32)
__device__ __forceinline__ void layer64(ushort_t* yb, const ushort_t* __restrict__ wg,
                                        const float* __restrict__ bias, int ml, int q,
                                        const bf16x8 B[4][2]) {
    f32x4 acc[8];
    #pragma unroll
    for (int t = 0; t < 8; ++t) acc[t] = f32x4{0.f, 0.f, 0.f, 0.f};
    gemmG<2>(wg, ml, q, B, acc);
    ep_silu2(yb, ml, q, acc, bias, 0);
    #pragma unroll
    for (int t = 0; t < 8; ++t) acc[t] = f32x4{0.f, 0.f, 0.f, 0.f};
    gemmG<2>(wg + 32*64, ml, q, B, acc);
    ep_silu2(yb, ml, q, acc, bias, 32);
}

// ---------------- main fused kernel: one block per row i ----------------
__global__ __launch_bounds__(256, 2) void egcl_kernel(
    const float* __restrict__ x, const float* __restrict__ h,
    const float* __restrict__ hw0, const float* __restrict__ hb0,
    const float* __restrict__ hw1, const float* __restrict__ hb1,
    const float* __restrict__ hw2, const float* __restrict__ hb2,
    const float* __restrict__ ws, float* __restrict__ out)
{
    __shared__ ushort_t ybuf[4][4608];    // per-wave acts [64 p][72], 9 KB each
    __shared__ float sbuf[4][64];
    __shared__ float pbuf[4][256];
    __shared__ float redm[4][64];
    __shared__ float reds[4][12];
    __shared__ float inbuf[128];
    __shared__ float zbuf[64];

    const int i = blockIdx.x, tid = threadIdx.x;
    const int wv = tid >> 6, lane = tid & 63;
    const int ml = lane & 15, q = lane >> 4;

    const ushort_t* wg = (const ushort_t*)(ws + WS_WG);
    const float* bias  = ws + WS_BIAS;

    if (wv == 1) inbuf[64 + lane] = h[i * 64 + lane];

    float xi[12];
    #pragma unroll
    for (int t = 0; t < 12; ++t) xi[t] = x[i * 12 + t];

    const float* Bi   = ws + WS_BI + i * 64;   // uniform -> s_load
    const float* w0at = ws + WS_W0AT;          // uniform -> s_load
    ushort_t* yb = ybuf[wv];

    float macc = 0.0f;
    float sacc[12];
    #pragma unroll
    for (int t = 0; t < 12; ++t) sacc[t] = 0.0f;

    #pragma unroll 1
    for (int it = 0; it < 3; ++it) {
        const int jg = it * 256 + wv * 64 + lane;

        float sqn[4];
        {
            const float4* xp = (const float4*)(x + jg * 12);
            float4 a = xp[0], b = xp[1], c = xp[2];
            float d0, d1, d2;
            d0=a.x-xi[0]; d1=a.y-xi[1]; d2=a.z-xi[2];   sqn[0]=d0*d0+d1*d1+d2*d2;
            d0=a.w-xi[3]; d1=b.x-xi[4]; d2=b.y-xi[5];   sqn[1]=d0*d0+d1*d1+d2*d2;
            d0=b.z-xi[6]; d1=b.w-xi[7]; d2=c.x-xi[8];   sqn[2]=d0*d0+d1*d1+d2*d2;
            d0=c.y-xi[9]; d1=c.z-xi[10];d2=c.w-xi[11];  sqn[3]=d0*d0+d1*d1+d2*d2;
        }

        // ---- phi_e L0 (VALU, K=4 + Bi + Bj); write y0[p=lane][k] b128-packed ----
        {
            const float* Bj = ws + WS_BJ + jg * 64;
            #pragma unroll
            for (int b = 0; b < 8; ++b) {
                float4 A = *(const float4*)(Bj + b*8);
                float4 Bv = *(const float4*)(Bj + b*8 + 4);
                float z[8] = {A.x, A.y, A.z, A.w, Bv.x, Bv.y, Bv.z, Bv.w};
                #pragma unroll
                for (int u = 0; u < 8; ++u) {
                    int l = b*8 + u;
                    float v = Bi[l] + z[u]
                            + sqn[0]*w0at[l*4+0] + sqn[1]*w0at[l*4+1]
                            + sqn[2]*w0at[l*4+2] + sqn[3]*w0at[l*4+3];
                    z[u] = silu_f(v);
                }
                uint4 pkv = make_uint4(pk2(z[0],z[1]), pk2(z[2],z[3]),
                                       pk2(z[4],z[5]), pk2(z[6],z[7]));
                *(uint4*)(yb + lane * 72 + b*8) = pkv;
            }
        }

        bf16x8 B[4][2];

        // ---- phi_e L1: m = silu(y0 @ W1 + b1) ----
        load_bfrags(yb, ml, q, B);
        layer64(yb, wg + 0, bias + 0, ml, q, B);     // m -> yb

        // ---- load m frags; phi_inf first (yb still holds m for the m_i loop) ----
        load_bfrags(yb, ml, q, B);
        {
            f32x4 accI[4];
            #pragma unroll
            for (int t = 0; t < 4; ++t) accI[t] = f32x4{0.f, 0.f, 0.f, 0.f};
            gemmG<1>(wg + 128*64, ml, q, B, accI);
            if (q == 0) {
                #pragma unroll
                for (int pt = 0; pt < 4; ++pt) sbuf[wv][pt*16 + ml] = accI[pt][0] + bias[128];
            }
        }
        {
            float sv = sbuf[wv][lane];
            float ea = (jg == i) ? 0.0f : sigm_f(sv);
            sbuf[wv][lane] = ea;
        }

        // ---- m_i partial: lane=l sums e_p * m[p][l] (m still in yb) ----
        #pragma unroll 8
        for (int j2 = 0; j2 < 64; ++j2) {
            float ev = sbuf[wv][j2];
            macc += ev * bf2f(yb[j2 * 72 + lane]);
        }

        // ---- phi_x L0 (B = m, already in regs; overwrites yb) ----
        layer64(yb, wg + 64*64, bias + 64, ml, q, B);   // y1 -> yb

        // ---- phi_x L1 ----
        load_bfrags(yb, ml, q, B);
        layer64(yb, wg + 144*64, bias + 144, ml, q, B); // y2 -> yb

        // ---- phi_x L2 (64 -> 4) ----
        load_bfrags(yb, ml, q, B);
        {
            f32x4 acc2[4];
            #pragma unroll
            for (int t = 0; t < 4; ++t) acc2[t] = f32x4{0.f, 0.f, 0.f, 0.f};
            gemmG<1>(wg + 208*64, ml, q, B, acc2);
            if (q == 0) {
                float4 bx2 = *(const float4*)(bias + 208);
                #pragma unroll
                for (int pt = 0; pt < 4; ++pt) {
                    float4 pv = make_float4(acc2[pt][0] + bx2.x, acc2[pt][1] + bx2.y,
                                            acc2[pt][2] + bx2.z, acc2[pt][3] + bx2.w);
                    *(float4*)(pbuf[wv] + (pt*16 + ml) * 4) = pv;
                }
            }
        }

        // ---- shift contributions (lane = p); dx recomputed (x is L1-hot) ----
        {
            float4 pv = *(const float4*)(pbuf[wv] + lane * 4);
            float pvh[4] = {pv.x, pv.y, pv.z, pv.w};
            float mask = (jg == i) ? 0.0f : 1.0f;
            const float4* xp = (const float4*)(x + jg * 12);
            float4 a = xp[0], b = xp[1], c = xp[2];
            float dxs[12];
            dxs[0]=a.x-xi[0]; dxs[1]=a.y-xi[1]; dxs[2]=a.z-xi[2];  dxs[3]=a.w-xi[3];
            dxs[4]=b.x-xi[4]; dxs[5]=b.y-xi[5]; dxs[6]=b.z-xi[6];  dxs[7]=b.w-xi[7];
            dxs[8]=c.x-xi[8]; dxs[9]=c.y-xi[9]; dxs[10]=c.z-xi[10];dxs[11]=c.w-xi[11];
            #pragma unroll
            for (int hh = 0; hh < 4; ++hh) {
                float nsq = (sqn[hh] == 0.0f) ? 1.0f : sqn[hh];
                float inv = mask * pvh[hh] * __builtin_amdgcn_rcpf(sqrtf(nsq) + 1.0f);
                #pragma unroll
                for (int d = 0; d < 3; ++d)
                    sacc[hh*3 + d] += dxs[hh*3 + d] * inv;
            }
        }
    }

    // shift: one butterfly at the end
    #pragma unroll
    for (int t = 0; t < 12; ++t) {
        float v = sacc[t];
        v += __shfl_xor(v, 1, 64);
        v += __shfl_xor(v, 2, 64);
        v += __shfl_xor(v, 4, 64);
        v += __shfl_xor(v, 8, 64);
        v += __shfl_xor(v, 16, 64);
        v += __shfl_xor(v, 32, 64);
        sacc[t] = v;
    }

    redm[wv][lane] = macc;
    if (lane == 0) {
        #pragma unroll
        for (int t = 0; t < 12; ++t) reds[wv][t] = sacc[t];
    }
    __syncthreads();

    if (wv == 0) {
        float mi = (redm[0][lane] + redm[1][lane] + redm[2][lane] + redm[3][lane])
                   * (1.0f / sqrtf(767.0f));
        inbuf[lane] = mi;

        if (lane < 12) {
            float sh = reds[0][lane] + reds[1][lane] + reds[2][lane] + reds[3][lane];
            out[i*12 + lane] = x[i*12 + lane] + sh * (1.0f / 767.0f);
        }

        float a = hb0[lane];
        #pragma unroll 8
        for (int k = 0; k < 128; ++k) a += inbuf[k] * hw0[k*64 + lane];
        zbuf[lane] = silu_f(a);

        a = hb1[lane];
        #pragma unroll 8
        for (int k = 0; k < 64; ++k) a += zbuf[k] * hw1[k*64 + lane];
        zbuf[lane] = silu_f(a);

        a = hb2[lane];
        #pragma unroll 8
        for (int k = 0; k < 64; ++k) a += zbuf[k] * hw2[k*64 + lane];
        out[9216 + i*64 + lane] = h[i*64 + lane] + a;
    }
}

extern "C" void kernel_launch(void* const* d_in, const int* in_sizes, int n_in,
                              void* d_out, int out_size, void* d_ws, size_t ws_size,
                              hipStream_t stream) {
    const float* x    = (const float*)d_in[0];
    const float* h    = (const float*)d_in[1];
    const float* ew0  = (const float*)d_in[2];
    const float* eb0  = (const float*)d_in[3];
    const float* ew1  = (const float*)d_in[4];
    const float* eb1  = (const float*)d_in[5];
    const float* infw = (const float*)d_in[6];
    const float* infb = (const float*)d_in[7];
    const float* xw0  = (const float*)d_in[8];
    const float* xb0  = (const float*)d_in[9];
    const float* xw1  = (const float*)d_in[10];
    const float* xb1  = (const float*)d_in[11];
    const float* xw2  = (const float*)d_in[12];
    const float* xb2  = (const float*)d_in[13];
    const float* hw0  = (const float*)d_in[14];
    const float* hb0  = (const float*)d_in[15];
    const float* hw1  = (const float*)d_in[16];
    const float* hb1  = (const float*)d_in[17];
    const float* hw2  = (const float*)d_in[18];
    const float* hb2  = (const float*)d_in[19];

    float* ws  = (float*)d_ws;
    float* out = (float*)d_out;

    prep_kernel<<<797, 64, 0, stream>>>(x, h, ew0, eb0, ew1, eb1, infw, infb,
                                        xw0, xb0, xw1, xb1, xw2, xb2, ws);
    egcl_kernel<<<768, 256, 0, stream>>>(x, h, hw0, hb0, hw1, hb1, hw2, hb2, ws, out);
}

// Round 8
// 203.767 us; speedup vs baseline: 2.0409x; 1.1328x over previous
//
#include <hip/hip_runtime.h>
#include <hip/hip_bf16.h>
#include <math.h>

// N=768, H=4, D=3, HDIM=64, HID=64. e_in[i,j] = [sqn(4) | hc[j](80) | hc[i](80)]
// z0 = sqn@W0a + Bj[j] + Bi[i]  (Bi includes b0 and the hc[i] half).
// A = weights from GLOBAL (28 KB, L2-hot); B = activations in per-wave LDS
// [p][k] stride 72. Each layer loads its FULL B fragment set then lets it die
// (no cross-section register holds); phi_inf is a VALU row-dot; per-chunk
// shift butterfly accumulates into LDS. All to keep live set < 128 VGPR —
// rounds 4-7 showed the allocator pins 128 and spills the excess to scratch.
//
// ws layout (float offsets):
#define WS_BJ    0         // Bj [768][64] f32
#define WS_BI    49152     // Bi [768][64] f32
#define WS_W0AT  98304     // W0a^T [64][4] f32
#define WS_BIAS  98560     // [224] f32: eb1@0, xb0@64, infb@128, 0, xb1@144, xb2@208, 0
#define WS_INFW  98784     // infw [64] f32 (for s_load row-dot)
#define WS_WG    98848     // bf16 [224 rows][64]: W1^T@0, X0^T@64, infw@128, 0, X1^T@144, X2^T@208, 0

typedef unsigned short ushort_t;
typedef __attribute__((ext_vector_type(8))) __bf16 bf16x8;
typedef __attribute__((ext_vector_type(4))) float f32x4;

__device__ __forceinline__ float silu_f(float v) {
    return v * __builtin_amdgcn_rcpf(1.0f + __expf(-v));
}
__device__ __forceinline__ float sigm_f(float v) {
    return __builtin_amdgcn_rcpf(1.0f + __expf(-v));
}

__device__ __forceinline__ ushort_t bf16r(float f) {
    unsigned u = __float_as_uint(f);
    u += 0x7FFFu + ((u >> 16) & 1u);
    return (ushort_t)(u >> 16);
}
__device__ __forceinline__ float bf2f(ushort_t s) { return __uint_as_float(((unsigned)s) << 16); }

__device__ __forceinline__ unsigned pk2(float a, float b) {
    __hip_bfloat162 t = __float22bfloat162_rn(make_float2(a, b));
    return *reinterpret_cast<unsigned*>(&t);
}

// ---------------- prep ----------------
__global__ __launch_bounds__(64) void prep_kernel(
    const float* __restrict__ x, const float* __restrict__ h,
    const float* __restrict__ ew0, const float* __restrict__ eb0,
    const float* __restrict__ ew1, const float* __restrict__ eb1,
    const float* __restrict__ infw, const float* __restrict__ infb,
    const float* __restrict__ xw0, const float* __restrict__ xb0,
    const float* __restrict__ xw1, const float* __restrict__ xb1,
    const float* __restrict__ xw2, const float* __restrict__ xb2,
    float* __restrict__ ws)
{
    const int blk = blockIdx.x, t = threadIdx.x;
    if (blk < 768) {
        __shared__ float hcs[80];
        const int m = blk;
        hcs[t] = h[m * 64 + t];
        if (t < 16) {
            int i2 = t >> 2, j2 = t & 3;
            float d0 = x[m*12 + j2*3 + 0] - x[m*12 + i2*3 + 0];
            float d1 = x[m*12 + j2*3 + 1] - x[m*12 + i2*3 + 1];
            float d2 = x[m*12 + j2*3 + 2] - x[m*12 + i2*3 + 2];
            hcs[64 + t] = d0*d0 + d1*d1 + d2*d2;
        }
        __syncthreads();
        float bj = 0.0f, bi = eb0[t];
        #pragma unroll 4
        for (int k = 0; k < 80; ++k) {
            float hv = hcs[k];
            bj += hv * ew0[(4 + k) * 64 + t];
            bi += hv * ew0[(84 + k) * 64 + t];
        }
        ws[WS_BJ + m * 64 + t] = bj;
        ws[WS_BI + m * 64 + t] = bi;
    } else if (blk == 768) {
        #pragma unroll
        for (int hh = 0; hh < 4; ++hh) ws[WS_W0AT + t * 4 + hh] = ew0[hh * 64 + t];
        ws[WS_INFW + t] = infw[t];
        #pragma unroll
        for (int u = 0; u < 4; ++u) {
            int idx = u * 64 + t;
            if (idx < 224) {
                float v;
                if (idx < 64)        v = eb1[idx];
                else if (idx < 128)  v = xb0[idx - 64];
                else if (idx == 128) v = infb[0];
                else if (idx < 144)  v = 0.0f;
                else if (idx < 208)  v = xb1[idx - 144];
                else if (idx < 212)  v = xb2[idx - 208];
                else                 v = 0.0f;
                ws[WS_BIAS + idx] = v;
            }
        }
    } else {
        ushort_t* wg = (ushort_t*)(ws + WS_WG);
        #pragma unroll 1
        for (int u = 0; u < 8; ++u) {
            int e = (blk - 769) * 512 + u * 64 + t;    // < 14336
            int r = e >> 6, k = e & 63;
            float v;
            if (r < 64)        v = ew1[k * 64 + r];
            else if (r < 128)  v = xw0[k * 64 + (r - 64)];
            else if (r == 128) v = infw[k];
            else if (r < 144)  v = 0.0f;
            else if (r < 208)  v = xw1[k * 64 + (r - 144)];
            else if (r < 212)  v = xw2[k * 4 + (r - 208)];
            else               v = 0.0f;
            wg[e] = bf16r(v);
        }
    }
}

// B-frags from per-wave LDS activations [p][k], stride 72
__device__ __forceinline__ void load_bfrags(const ushort_t* yb, int ml, int q, bf16x8 B[4][2]) {
    #pragma unroll
    for (int pt = 0; pt < 4; ++pt)
        #pragma unroll
        for (int kt = 0; kt < 2; ++kt)
            B[pt][kt] = *(const bf16x8*)(yb + (pt*16 + ml) * 72 + kt*32 + q*8);
}

// A-frags from GLOBAL weight image (rows x 64, row-major, L2-hot).
template<int NMT>
__device__ __forceinline__ void gemmG(const ushort_t* __restrict__ wg, int ml, int q,
                                      const bf16x8 B[4][2], f32x4* acc) {
    #pragma unroll
    for (int mt = 0; mt < NMT; ++mt) {
        #pragma unroll
        for (int kt = 0; kt < 2; ++kt) {
            bf16x8 af = *(const bf16x8*)(wg + (mt*16 + ml) * 64 + kt*32 + q*8);
            #pragma unroll
            for (int pt = 0; pt < 4; ++pt)
                acc[mt*4 + pt] = __builtin_amdgcn_mfma_f32_16x16x32_bf16(af, B[pt][kt], acc[mt*4 + pt], 0, 0, 0);
        }
    }
}

// epilogue for one mt-half (2 tiles): y[p][coff + n'] = bf16(silu(acc + bias))
__device__ __forceinline__ void ep_silu2(ushort_t* yb, int ml, int q,
                                         const f32x4* acc, const float* __restrict__ bias,
                                         int coff) {
    #pragma unroll
    for (int mt = 0; mt < 2; ++mt) {
        float4 bv = *(const float4*)(bias + coff + mt*16 + q*4);
        #pragma unroll
        for (int pt = 0; pt < 4; ++pt) {
            f32x4 a = acc[mt*4 + pt];
            uint2 w = make_uint2(pk2(silu_f(a[0] + bv.x), silu_f(a[1] + bv.y)),
                                 pk2(silu_f(a[2] + bv.z), silu_f(a[3] + bv.w)));
            *(uint2*)(yb + (pt*16 + ml) * 72 + coff + mt*16 + q*4) = w;
        }
    }
}

// one full 64x64 layer: loads its own full B set, two mt-halves of acc[8]
__device__ __forceinline__ void layer64(ushort_t* yb, const ushort_t* __restrict__ wg,
                                        const float* __restrict__ bias, int ml, int q) {
    bf16x8 B[4][2];
    load_bfrags(yb, ml, q, B);
    f32x4 acc[8];
    #pragma unroll
    for (int t = 0; t < 8; ++t) acc[t] = f32x4{0.f, 0.f, 0.f, 0.f};
    gemmG<2>(wg, ml, q, B, acc);
    ep_silu2(yb, ml, q, acc, bias, 0);
    #pragma unroll
    for (int t = 0; t < 8; ++t) acc[t] = f32x4{0.f, 0.f, 0.f, 0.f};
    gemmG<2>(wg + 32*64, ml, q, B, acc);
    ep_silu2(yb, ml, q, acc, bias, 32);
}

// ---------------- main fused kernel: one block per row i ----------------
__global__ __launch_bounds__(256, 2) void egcl_kernel(
    const float* __restrict__ x, const float* __restrict__ h,
    const float* __restrict__ hw0, const float* __restrict__ hb0,
    const float* __restrict__ hw1, const float* __restrict__ hb1,
    const float* __restrict__ hw2, const float* __restrict__ hb2,
    const float* __restrict__ ws, float* __restrict__ out)
{
    __shared__ ushort_t ybuf[4][4608];    // per-wave acts [64 p][72], 9 KB each
    __shared__ float sbuf[4][64];
    __shared__ float pbuf[4][256];
    __shared__ float redm[4][64];
    __shared__ float reds[4][12];
    __shared__ float inbuf[128];
    __shared__ float zbuf[64];

    const int i = blockIdx.x, tid = threadIdx.x;
    const int wv = tid >> 6, lane = tid & 63;
    const int ml = lane & 15, q = lane >> 4;

    const ushort_t* wg = (const ushort_t*)(ws + WS_WG);
    const float* bias  = ws + WS_BIAS;
    const float* infwf = ws + WS_INFW;

    if (wv == 1) inbuf[64 + lane] = h[i * 64 + lane];
    if (lane < 12) reds[wv][lane] = 0.0f;

    float xi[12];
    #pragma unroll
    for (int t = 0; t < 12; ++t) xi[t] = x[i * 12 + t];

    const float* Bi   = ws + WS_BI + i * 64;   // uniform -> s_load
    const float* w0at = ws + WS_W0AT;          // uniform -> s_load
    ushort_t* yb = ybuf[wv];

    float macc = 0.0f;

    #pragma unroll 1
    for (int it = 0; it < 3; ++it) {
        const int jg = it * 256 + wv * 64 + lane;

        float sqn[4];
        {
            const float4* xp = (const float4*)(x + jg * 12);
            float4 a = xp[0], b = xp[1], c = xp[2];
            float d0, d1, d2;
            d0=a.x-xi[0]; d1=a.y-xi[1]; d2=a.z-xi[2];   sqn[0]=d0*d0+d1*d1+d2*d2;
            d0=a.w-xi[3]; d1=b.x-xi[4]; d2=b.y-xi[5];   sqn[1]=d0*d0+d1*d1+d2*d2;
            d0=b.z-xi[6]; d1=b.w-xi[7]; d2=c.x-xi[8];   sqn[2]=d0*d0+d1*d1+d2*d2;
            d0=c.y-xi[9]; d1=c.z-xi[10];d2=c.w-xi[11];  sqn[3]=d0*d0+d1*d1+d2*d2;
        }

        // ---- phi_e L0 (VALU, K=4 + Bi + Bj); write y0[p=lane][k] b128-packed ----
        {
            const float* Bj = ws + WS_BJ + jg * 64;
            #pragma unroll
            for (int b = 0; b < 8; ++b) {
                float4 A = *(const float4*)(Bj + b*8);
                float4 Bv = *(const float4*)(Bj + b*8 + 4);
                float z[8] = {A.x, A.y, A.z, A.w, Bv.x, Bv.y, Bv.z, Bv.w};
                #pragma unroll
                for (int u = 0; u < 8; ++u) {
                    int l = b*8 + u;
                    float v = Bi[l] + z[u]
                            + sqn[0]*w0at[l*4+0] + sqn[1]*w0at[l*4+1]
                            + sqn[2]*w0at[l*4+2] + sqn[3]*w0at[l*4+3];
                    z[u] = silu_f(v);
                }
                uint4 pkv = make_uint4(pk2(z[0],z[1]), pk2(z[2],z[3]),
                                       pk2(z[4],z[5]), pk2(z[6],z[7]));
                *(uint4*)(yb + lane * 72 + b*8) = pkv;
            }
        }

        // ---- phi_e L1: m = silu(y0 @ W1 + b1) ----
        layer64(yb, wg + 0, bias + 0, ml, q);        // m -> yb

        // ---- phi_inf as VALU row-dot: s_inf[p=lane] = infb + infw . m[lane][:] ----
        {
            float sv = bias[128];
            #pragma unroll
            for (int c = 0; c < 8; ++c) {
                uint2 w0 = *(const uint2*)(yb + lane * 72 + c*8);
                uint2 w1 = *(const uint2*)(yb + lane * 72 + c*8 + 4);
                sv += __uint_as_float(w0.x << 16)          * infwf[c*8 + 0];
                sv += __uint_as_float(w0.x & 0xFFFF0000u)  * infwf[c*8 + 1];
                sv += __uint_as_float(w0.y << 16)          * infwf[c*8 + 2];
                sv += __uint_as_float(w0.y & 0xFFFF0000u)  * infwf[c*8 + 3];
                sv += __uint_as_float(w1.x << 16)          * infwf[c*8 + 4];
                sv += __uint_as_float(w1.x & 0xFFFF0000u)  * infwf[c*8 + 5];
                sv += __uint_as_float(w1.y << 16)          * infwf[c*8 + 6];
                sv += __uint_as_float(w1.y & 0xFFFF0000u)  * infwf[c*8 + 7];
            }
            sbuf[wv][lane] = (jg == i) ? 0.0f : sigm_f(sv);
        }

        // ---- m_i partial: lane=l sums e_p * m[p][l] (m still in yb) ----
        #pragma unroll 8
        for (int j2 = 0; j2 < 64; ++j2) {
            float ev = sbuf[wv][j2];
            macc += ev * bf2f(yb[j2 * 72 + lane]);
        }

        // ---- phi_x L0, L1 (each loads its own B; yb overwritten after load) ----
        layer64(yb, wg + 64*64, bias + 64, ml, q);   // y1 -> yb
        layer64(yb, wg + 144*64, bias + 144, ml, q); // y2 -> yb

        // ---- phi_x L2 (64 -> 4) ----
        {
            bf16x8 B[4][2];
            load_bfrags(yb, ml, q, B);
            f32x4 acc2[4];
            #pragma unroll
            for (int t = 0; t < 4; ++t) acc2[t] = f32x4{0.f, 0.f, 0.f, 0.f};
            gemmG<1>(wg + 208*64, ml, q, B, acc2);
            if (q == 0) {
                float4 bx2 = *(const float4*)(bias + 208);
                #pragma unroll
                for (int pt = 0; pt < 4; ++pt) {
                    float4 pv = make_float4(acc2[pt][0] + bx2.x, acc2[pt][1] + bx2.y,
                                            acc2[pt][2] + bx2.z, acc2[pt][3] + bx2.w);
                    *(float4*)(pbuf[wv] + (pt*16 + ml) * 4) = pv;
                }
            }
        }

        // ---- shift contributions (lane = p); per-chunk butterfly -> LDS ----
        {
            float4 pv = *(const float4*)(pbuf[wv] + lane * 4);
            float pvh[4] = {pv.x, pv.y, pv.z, pv.w};
            float mask = (jg == i) ? 0.0f : 1.0f;
            const float4* xp = (const float4*)(x + jg * 12);
            float4 a = xp[0], b = xp[1], c = xp[2];
            float dxs[12];
            dxs[0]=a.x-xi[0]; dxs[1]=a.y-xi[1]; dxs[2]=a.z-xi[2];  dxs[3]=a.w-xi[3];
            dxs[4]=b.x-xi[4]; dxs[5]=b.y-xi[5]; dxs[6]=b.z-xi[6];  dxs[7]=b.w-xi[7];
            dxs[8]=c.x-xi[8]; dxs[9]=c.y-xi[9]; dxs[10]=c.z-xi[10];dxs[11]=c.w-xi[11];
            float s12[12];
            #pragma unroll
            for (int hh = 0; hh < 4; ++hh) {
                float nsq = (sqn[hh] == 0.0f) ? 1.0f : sqn[hh];
                float inv = mask * pvh[hh] * __builtin_amdgcn_rcpf(sqrtf(nsq) + 1.0f);
                #pragma unroll
                for (int d = 0; d < 3; ++d)
                    s12[hh*3 + d] = dxs[hh*3 + d] * inv;
            }
            #pragma unroll
            for (int t = 0; t < 12; ++t) {
                float v = s12[t];
                v += __shfl_xor(v, 1, 64);
                v += __shfl_xor(v, 2, 64);
                v += __shfl_xor(v, 4, 64);
                v += __shfl_xor(v, 8, 64);
                v += __shfl_xor(v, 16, 64);
                v += __shfl_xor(v, 32, 64);
                if (lane == 0) reds[wv][t] += v;
            }
        }
    }

    redm[wv][lane] = macc;
    __syncthreads();

    if (wv == 0) {
        float mi = (redm[0][lane] + redm[1][lane] + redm[2][lane] + redm[3][lane])
                   * (1.0f / sqrtf(767.0f));
        inbuf[lane] = mi;

        if (lane < 12) {
            float sh = reds[0][lane] + reds[1][lane] + reds[2][lane] + reds[3][lane];
            out[i*12 + lane] = x[i*12 + lane] + sh * (1.0f / 767.0f);
        }

        float a = hb0[lane];
        #pragma unroll 8
        for (int k = 0; k < 128; ++k) a += inbuf[k] * hw0[k*64 + lane];
        zbuf[lane] = silu_f(a);

        a = hb1[lane];
        #pragma unroll 8
        for (int k = 0; k < 64; ++k) a += zbuf[k] * hw1[k*64 + lane];
        zbuf[lane] = silu_f(a);

        a = hb2[lane];
        #pragma unroll 8
        for (int k = 0; k < 64; ++k) a += zbuf[k] * hw2[k*64 + lane];
        out[9216 + i*64 + lane] = h[i*64 + lane] + a;
    }
}

extern "C" void kernel_launch(void* const* d_in, const int* in_sizes, int n_in,
                              void* d_out, int out_size, void* d_ws, size_t ws_size,
                              hipStream_t stream) {
    const float* x    = (const float*)d_in[0];
    const float* h    = (const float*)d_in[1];
    const float* ew0  = (const float*)d_in[2];
    const float* eb0  = (const float*)d_in[3];
    const float* ew1  = (const float*)d_in[4];
    const float* eb1  = (const float*)d_in[5];
    const float* infw = (const float*)d_in[6];
    const float* infb = (const float*)d_in[7];
    const float* xw0  = (const float*)d_in[8];
    const float* xb0  = (const float*)d_in[9];
    const float* xw1  = (const float*)d_in[10];
    const float* xb1  = (const float*)d_in[11];
    const float* xw2  = (const float*)d_in[12];
    const float* xb2  = (const float*)d_in[13];
    const float* hw0  = (const float*)d_in[14];
    const float* hb0  = (const float*)d_in[15];
    const float* hw1  = (const float*)d_in[16];
    const float* hb1  = (const float*)d_in[17];
    const float* hw2  = (const float*)d_in[18];
    const float* hb2  = (const float*)d_in[19];

    float* ws  = (float*)d_ws;
    float* out = (float*)d_out;

    prep_kernel<<<797, 64, 0, stream>>>(x, h, ew0, eb0, ew1, eb1, infw, infb,
                                        xw0, xb0, xw1, xb1, xw2, xb2, ws);
    egcl_kernel<<<768, 256, 0, stream>>>(x, h, hw0, hb0, hw1, hb1, hw2, hb2, ws, out);
}

// Round 9
// 170.982 us; speedup vs baseline: 2.4322x; 1.1917x over previous
//
#include <hip/hip_runtime.h>
#include <hip/hip_bf16.h>
#include <math.h>

// N=768, H=4, D=3, HDIM=64, HID=64. e_in[i,j] = [sqn(4) | hc[j](80) | hc[i](80)]
// z0 = sqn@W0a + Bj[j] + Bi[i]  (Bi includes b0 and the hc[i] half).
// Round 9: grid (3 chunks, 768 rows) — one 256-pair chunk per block (short
// critical path, 2304 independent blocks); partial m_i/shift to ws; finish
// kernel sums 3 partials + phi_h + x_new. LDS 39 KB -> 4 blocks/CU.
//
// ws layout (float offsets):
#define WS_BJ    0         // Bj [768][64] f32
#define WS_BI    49152     // Bi [768][64] f32
#define WS_W0AT  98304     // W0a^T [64][4] f32
#define WS_BIAS  98560     // [224] f32: eb1@0, xb0@64, infb@128, 0, xb1@144, xb2@208, 0
#define WS_INFW  98784     // infw [64] f32
#define WS_WG    98848     // bf16 [224 rows][64] = 7168 floats
#define WS_PM    106016    // m_i partials [768][3][64] f32
#define WS_PS    253472    // shift partials [768][3][12] f32  (ends 281120)

typedef unsigned short ushort_t;
typedef __attribute__((ext_vector_type(8))) __bf16 bf16x8;
typedef __attribute__((ext_vector_type(4))) float f32x4;

__device__ __forceinline__ float silu_f(float v) {
    return v * __builtin_amdgcn_rcpf(1.0f + __expf(-v));
}
__device__ __forceinline__ float sigm_f(float v) {
    return __builtin_amdgcn_rcpf(1.0f + __expf(-v));
}

__device__ __forceinline__ ushort_t bf16r(float f) {
    unsigned u = __float_as_uint(f);
    u += 0x7FFFu + ((u >> 16) & 1u);
    return (ushort_t)(u >> 16);
}
__device__ __forceinline__ float bf2f(ushort_t s) { return __uint_as_float(((unsigned)s) << 16); }

__device__ __forceinline__ unsigned pk2(float a, float b) {
    __hip_bfloat162 t = __float22bfloat162_rn(make_float2(a, b));
    return *reinterpret_cast<unsigned*>(&t);
}

// ---------------- prep (256-thread blocks) ----------------
__global__ __launch_bounds__(256) void prep_kernel(
    const float* __restrict__ x, const float* __restrict__ h,
    const float* __restrict__ ew0, const float* __restrict__ eb0,
    const float* __restrict__ ew1, const float* __restrict__ eb1,
    const float* __restrict__ infw, const float* __restrict__ infb,
    const float* __restrict__ xw0, const float* __restrict__ xb0,
    const float* __restrict__ xw1, const float* __restrict__ xb1,
    const float* __restrict__ xw2, const float* __restrict__ xb2,
    float* __restrict__ ws)
{
    const int blk = blockIdx.x, tid = threadIdx.x;
    const int wv = tid >> 6, t = tid & 63;
    if (blk < 192) {
        __shared__ float hcs[4][80];
        const int m = blk * 4 + wv;
        hcs[wv][t] = h[m * 64 + t];
        if (t < 16) {
            int i2 = t >> 2, j2 = t & 3;
            float d0 = x[m*12 + j2*3 + 0] - x[m*12 + i2*3 + 0];
            float d1 = x[m*12 + j2*3 + 1] - x[m*12 + i2*3 + 1];
            float d2 = x[m*12 + j2*3 + 2] - x[m*12 + i2*3 + 2];
            hcs[wv][64 + t] = d0*d0 + d1*d1 + d2*d2;
        }
        float bj = 0.0f, bi = eb0[t];
        #pragma unroll 4
        for (int k = 0; k < 80; ++k) {
            float hv = hcs[wv][k];
            bj += hv * ew0[(4 + k) * 64 + t];
            bi += hv * ew0[(84 + k) * 64 + t];
        }
        ws[WS_BJ + m * 64 + t] = bj;
        ws[WS_BI + m * 64 + t] = bi;
    } else if (blk == 192) {
        if (wv == 0) {
            #pragma unroll
            for (int hh = 0; hh < 4; ++hh) ws[WS_W0AT + t * 4 + hh] = ew0[hh * 64 + t];
            ws[WS_INFW + t] = infw[t];
            #pragma unroll
            for (int u = 0; u < 4; ++u) {
                int idx = u * 64 + t;
                if (idx < 224) {
                    float v;
                    if (idx < 64)        v = eb1[idx];
                    else if (idx < 128)  v = xb0[idx - 64];
                    else if (idx == 128) v = infb[0];
                    else if (idx < 144)  v = 0.0f;
                    else if (idx < 208)  v = xb1[idx - 144];
                    else if (idx < 212)  v = xb2[idx - 208];
                    else                 v = 0.0f;
                    ws[WS_BIAS + idx] = v;
                }
            }
        }
    } else {
        ushort_t* wg = (ushort_t*)(ws + WS_WG);
        #pragma unroll 1
        for (int u = 0; u < 8; ++u) {
            int e = (blk - 193) * 2048 + tid * 8 + u;   // < 14336
            int r = e >> 6, k = e & 63;
            float v;
            if (r < 64)        v = ew1[k * 64 + r];
            else if (r < 128)  v = xw0[k * 64 + (r - 64)];
            else if (r == 128) v = infw[k];
            else if (r < 144)  v = 0.0f;
            else if (r < 208)  v = xw1[k * 64 + (r - 144)];
            else if (r < 212)  v = xw2[k * 4 + (r - 208)];
            else               v = 0.0f;
            wg[e] = bf16r(v);
        }
    }
}

// B-frags from per-wave LDS activations [p][k], stride 72
__device__ __forceinline__ void load_bfrags(const ushort_t* yb, int ml, int q, bf16x8 B[4][2]) {
    #pragma unroll
    for (int pt = 0; pt < 4; ++pt)
        #pragma unroll
        for (int kt = 0; kt < 2; ++kt)
            B[pt][kt] = *(const bf16x8*)(yb + (pt*16 + ml) * 72 + kt*32 + q*8);
}

template<int NMT>
__device__ __forceinline__ void gemmG(const ushort_t* __restrict__ wg, int ml, int q,
                                      const bf16x8 B[4][2], f32x4* acc) {
    #pragma unroll
    for (int mt = 0; mt < NMT; ++mt) {
        #pragma unroll
        for (int kt = 0; kt < 2; ++kt) {
            bf16x8 af = *(const bf16x8*)(wg + (mt*16 + ml) * 64 + kt*32 + q*8);
            #pragma unroll
            for (int pt = 0; pt < 4; ++pt)
                acc[mt*4 + pt] = __builtin_amdgcn_mfma_f32_16x16x32_bf16(af, B[pt][kt], acc[mt*4 + pt], 0, 0, 0);
        }
    }
}

__device__ __forceinline__ void ep_silu2(ushort_t* yb, int ml, int q,
                                         const f32x4* acc, const float* __restrict__ bias,
                                         int coff) {
    #pragma unroll
    for (int mt = 0; mt < 2; ++mt) {
        float4 bv = *(const float4*)(bias + coff + mt*16 + q*4);
        #pragma unroll
        for (int pt = 0; pt < 4; ++pt) {
            f32x4 a = acc[mt*4 + pt];
            uint2 w = make_uint2(pk2(silu_f(a[0] + bv.x), silu_f(a[1] + bv.y)),
                                 pk2(silu_f(a[2] + bv.z), silu_f(a[3] + bv.w)));
            *(uint2*)(yb + (pt*16 + ml) * 72 + coff + mt*16 + q*4) = w;
        }
    }
}

__device__ __forceinline__ void layer64(ushort_t* yb, const ushort_t* __restrict__ wg,
                                        const float* __restrict__ bias, int ml, int q) {
    bf16x8 B[4][2];
    load_bfrags(yb, ml, q, B);
    f32x4 acc[8];
    #pragma unroll
    for (int t = 0; t < 8; ++t) acc[t] = f32x4{0.f, 0.f, 0.f, 0.f};
    gemmG<2>(wg, ml, q, B, acc);
    ep_silu2(yb, ml, q, acc, bias, 0);
    #pragma unroll
    for (int t = 0; t < 8; ++t) acc[t] = f32x4{0.f, 0.f, 0.f, 0.f};
    gemmG<2>(wg + 32*64, ml, q, B, acc);
    ep_silu2(yb, ml, q, acc, bias, 32);
}

// ---------------- chunk kernel: block = (chunk it, row i), 256 pairs ----------------
__global__ __launch_bounds__(256, 2) void egcl_chunk(
    const float* __restrict__ x, float* __restrict__ ws)
{
    __shared__ ushort_t ybuf[4][4608];    // per-wave acts [64 p][72], 9 KB each
    __shared__ float sbuf[4][64];
    __shared__ float redm[4][64];
    __shared__ float reds[4][12];

    const int it = blockIdx.x, i = blockIdx.y, tid = threadIdx.x;
    const int wv = tid >> 6, lane = tid & 63;
    const int ml = lane & 15, q = lane >> 4;
    const int jg = it * 256 + wv * 64 + lane;

    const ushort_t* wg = (const ushort_t*)(ws + WS_WG);
    const float* bias  = ws + WS_BIAS;
    const float* infwf = ws + WS_INFW;
    const float* Bi    = ws + WS_BI + i * 64;   // uniform -> s_load
    const float* w0at  = ws + WS_W0AT;          // uniform -> s_load
    ushort_t* yb = ybuf[wv];

    float xi[12];
    #pragma unroll
    for (int t = 0; t < 12; ++t) xi[t] = x[i * 12 + t];

    float sqn[4];
    {
        const float4* xp = (const float4*)(x + jg * 12);
        float4 a = xp[0], b = xp[1], c = xp[2];
        float d0, d1, d2;
        d0=a.x-xi[0]; d1=a.y-xi[1]; d2=a.z-xi[2];   sqn[0]=d0*d0+d1*d1+d2*d2;
        d0=a.w-xi[3]; d1=b.x-xi[4]; d2=b.y-xi[5];   sqn[1]=d0*d0+d1*d1+d2*d2;
        d0=b.z-xi[6]; d1=b.w-xi[7]; d2=c.x-xi[8];   sqn[2]=d0*d0+d1*d1+d2*d2;
        d0=c.y-xi[9]; d1=c.z-xi[10];d2=c.w-xi[11];  sqn[3]=d0*d0+d1*d1+d2*d2;
    }

    // ---- phi_e L0 (VALU, K=4 + Bi + Bj); write y0[p=lane][k] b128-packed ----
    {
        const float* Bj = ws + WS_BJ + jg * 64;
        #pragma unroll
        for (int b = 0; b < 8; ++b) {
            float4 A = *(const float4*)(Bj + b*8);
            float4 Bv = *(const float4*)(Bj + b*8 + 4);
            float z[8] = {A.x, A.y, A.z, A.w, Bv.x, Bv.y, Bv.z, Bv.w};
            #pragma unroll
            for (int u = 0; u < 8; ++u) {
                int l = b*8 + u;
                float v = Bi[l] + z[u]
                        + sqn[0]*w0at[l*4+0] + sqn[1]*w0at[l*4+1]
                        + sqn[2]*w0at[l*4+2] + sqn[3]*w0at[l*4+3];
                z[u] = silu_f(v);
            }
            uint4 pkv = make_uint4(pk2(z[0],z[1]), pk2(z[2],z[3]),
                                   pk2(z[4],z[5]), pk2(z[6],z[7]));
            *(uint4*)(yb + lane * 72 + b*8) = pkv;
        }
    }

    // ---- phi_e L1: m = silu(y0 @ W1 + b1) ----
    layer64(yb, wg + 0, bias + 0, ml, q);        // m -> yb

    // ---- phi_inf VALU row-dot: s_inf[p=lane] = infb + infw . m[lane][:] ----
    {
        float sv = bias[128];
        #pragma unroll
        for (int c = 0; c < 8; ++c) {
            uint2 w0 = *(const uint2*)(yb + lane * 72 + c*8);
            uint2 w1 = *(const uint2*)(yb + lane * 72 + c*8 + 4);
            sv += __uint_as_float(w0.x << 16)          * infwf[c*8 + 0];
            sv += __uint_as_float(w0.x & 0xFFFF0000u)  * infwf[c*8 + 1];
            sv += __uint_as_float(w0.y << 16)          * infwf[c*8 + 2];
            sv += __uint_as_float(w0.y & 0xFFFF0000u)  * infwf[c*8 + 3];
            sv += __uint_as_float(w1.x << 16)          * infwf[c*8 + 4];
            sv += __uint_as_float(w1.x & 0xFFFF0000u)  * infwf[c*8 + 5];
            sv += __uint_as_float(w1.y << 16)          * infwf[c*8 + 6];
            sv += __uint_as_float(w1.y & 0xFFFF0000u)  * infwf[c*8 + 7];
        }
        sbuf[wv][lane] = (jg == i) ? 0.0f : sigm_f(sv);
    }

    // ---- m_i partial: lane=l sums e_p * m[p][l] (m still in yb) ----
    float macc = 0.0f;
    #pragma unroll 8
    for (int j2 = 0; j2 < 64; ++j2) {
        float ev = sbuf[wv][j2];
        macc += ev * bf2f(yb[j2 * 72 + lane]);
    }

    // ---- phi_x L0, L1 ----
    layer64(yb, wg + 64*64, bias + 64, ml, q);   // y1 -> yb
    layer64(yb, wg + 144*64, bias + 144, ml, q); // y2 -> yb

    // ---- phi_x L2 (64 -> 4); p overlaid into dead yb as f32 ----
    float* yf = (float*)yb;
    {
        bf16x8 B[4][2];
        load_bfrags(yb, ml, q, B);
        f32x4 acc2[4];
        #pragma unroll
        for (int t = 0; t < 4; ++t) acc2[t] = f32x4{0.f, 0.f, 0.f, 0.f};
        gemmG<1>(wg + 208*64, ml, q, B, acc2);
        if (q == 0) {
            float4 bx2 = *(const float4*)(bias + 208);
            #pragma unroll
            for (int pt = 0; pt < 4; ++pt) {
                float4 pv = make_float4(acc2[pt][0] + bx2.x, acc2[pt][1] + bx2.y,
                                        acc2[pt][2] + bx2.z, acc2[pt][3] + bx2.w);
                *(float4*)(yf + (pt*16 + ml) * 4) = pv;
            }
        }
    }

    // ---- shift contributions (lane = p); butterfly -> reds ----
    {
        float4 pv = *(const float4*)(yf + lane * 4);
        float pvh[4] = {pv.x, pv.y, pv.z, pv.w};
        float mask = (jg == i) ? 0.0f : 1.0f;
        const float4* xp = (const float4*)(x + jg * 12);
        float4 a = xp[0], b = xp[1], c = xp[2];
        float dxs[12];
        dxs[0]=a.x-xi[0]; dxs[1]=a.y-xi[1]; dxs[2]=a.z-xi[2];  dxs[3]=a.w-xi[3];
        dxs[4]=b.x-xi[4]; dxs[5]=b.y-xi[5]; dxs[6]=b.z-xi[6];  dxs[7]=b.w-xi[7];
        dxs[8]=c.x-xi[8]; dxs[9]=c.y-xi[9]; dxs[10]=c.z-xi[10];dxs[11]=c.w-xi[11];
        float s12[12];
        #pragma unroll
        for (int hh = 0; hh < 4; ++hh) {
            float nsq = (sqn[hh] == 0.0f) ? 1.0f : sqn[hh];
            float inv = mask * pvh[hh] * __builtin_amdgcn_rcpf(sqrtf(nsq) + 1.0f);
            #pragma unroll
            for (int d = 0; d < 3; ++d)
                s12[hh*3 + d] = dxs[hh*3 + d] * inv;
        }
        #pragma unroll
        for (int t = 0; t < 12; ++t) {
            float v = s12[t];
            v += __shfl_xor(v, 1, 64);
            v += __shfl_xor(v, 2, 64);
            v += __shfl_xor(v, 4, 64);
            v += __shfl_xor(v, 8, 64);
            v += __shfl_xor(v, 16, 64);
            v += __shfl_xor(v, 32, 64);
            if (lane == 0) reds[wv][t] = v;
        }
    }

    redm[wv][lane] = macc;
    __syncthreads();

    if (wv == 0) {
        ws[WS_PM + (i*3 + it)*64 + lane] =
            redm[0][lane] + redm[1][lane] + redm[2][lane] + redm[3][lane];
        if (lane < 12)
            ws[WS_PS + (i*3 + it)*12 + lane] =
                reds[0][lane] + reds[1][lane] + reds[2][lane] + reds[3][lane];
    }
}

// ---------------- finish: sum partials + phi_h + x_new ----------------
__global__ __launch_bounds__(64) void finish_kernel(
    const float* __restrict__ x, const float* __restrict__ h,
    const float* __restrict__ hw0, const float* __restrict__ hb0,
    const float* __restrict__ hw1, const float* __restrict__ hb1,
    const float* __restrict__ hw2, const float* __restrict__ hb2,
    const float* __restrict__ ws, float* __restrict__ out)
{
    __shared__ float inbuf[128];
    __shared__ float zbuf[64];
    const int i = blockIdx.x, lane = threadIdx.x;

    const float* pm = ws + WS_PM + i*3*64;
    float mi = (pm[lane] + pm[64 + lane] + pm[128 + lane]) * (1.0f / sqrtf(767.0f));
    inbuf[lane] = mi;
    inbuf[64 + lane] = h[i*64 + lane];

    if (lane < 12) {
        const float* ps = ws + WS_PS + i*3*12;
        float sh = ps[lane] + ps[12 + lane] + ps[24 + lane];
        out[i*12 + lane] = x[i*12 + lane] + sh * (1.0f / 767.0f);
    }

    // single wave: LDS ops in-order, no barrier needed
    float a = hb0[lane];
    #pragma unroll 8
    for (int k = 0; k < 128; ++k) a += inbuf[k] * hw0[k*64 + lane];
    zbuf[lane] = silu_f(a);

    a = hb1[lane];
    #pragma unroll 8
    for (int k = 0; k < 64; ++k) a += zbuf[k] * hw1[k*64 + lane];
    zbuf[lane] = silu_f(a);

    a = hb2[lane];
    #pragma unroll 8
    for (int k = 0; k < 64; ++k) a += zbuf[k] * hw2[k*64 + lane];
    out[9216 + i*64 + lane] = h[i*64 + lane] + a;
}

extern "C" void kernel_launch(void* const* d_in, const int* in_sizes, int n_in,
                              void* d_out, int out_size, void* d_ws, size_t ws_size,
                              hipStream_t stream) {
    const float* x    = (const float*)d_in[0];
    const float* h    = (const float*)d_in[1];
    const float* ew0  = (const float*)d_in[2];
    const float* eb0  = (const float*)d_in[3];
    const float* ew1  = (const float*)d_in[4];
    const float* eb1  = (const float*)d_in[5];
    const float* infw = (const float*)d_in[6];
    const float* infb = (const float*)d_in[7];
    const float* xw0  = (const float*)d_in[8];
    const float* xb0  = (const float*)d_in[9];
    const float* xw1  = (const float*)d_in[10];
    const float* xb1  = (const float*)d_in[11];
    const float* xw2  = (const float*)d_in[12];
    const float* xb2  = (const float*)d_in[13];
    const float* hw0  = (const float*)d_in[14];
    const float* hb0  = (const float*)d_in[15];
    const float* hw1  = (const float*)d_in[16];
    const float* hb1  = (const float*)d_in[17];
    const float* hw2  = (const float*)d_in[18];
    const float* hb2  = (const float*)d_in[19];

    float* ws  = (float*)d_ws;
    float* out = (float*)d_out;

    prep_kernel<<<200, 256, 0, stream>>>(x, h, ew0, eb0, ew1, eb1, infw, infb,
                                         xw0, xb0, xw1, xb1, xw2, xb2, ws);
    egcl_chunk<<<dim3(3, 768), 256, 0, stream>>>(x, ws);
    finish_kernel<<<768, 64, 0, stream>>>(x, h, hw0, hb0, hw1, hb1, hw2, hb2, ws, out);
}